// Round 2
// baseline (590.764 us; speedup 1.0000x reference)
//
#include <hip/hip_runtime.h>
#include <hip/hip_bf16.h>

typedef __bf16 bf16_t;
typedef __bf16 bf16x8 __attribute__((ext_vector_type(8)));
typedef __bf16 bf16x4 __attribute__((ext_vector_type(4)));
typedef float  f32x4  __attribute__((ext_vector_type(4)));

#define NB 2
#define NS 2048
#define ND 2048
#define NH 16
#define QLORA 1536
#define KVLORA 512
#define DNOPE 128
#define DROPE 64
#define DVDIM 128
#define QKD 192

// ---------------- f32 -> bf16 convert (vectorized) ----------------
__global__ void k_cvt(const float* __restrict__ in, bf16_t* __restrict__ out, int n4) {
  int i = blockIdx.x * blockDim.x + threadIdx.x;
  int stride = gridDim.x * blockDim.x;
  for (; i < n4; i += stride) {
    float4 v = reinterpret_cast<const float4*>(in)[i];
    bf16x4 o = {(bf16_t)v.x, (bf16_t)v.y, (bf16_t)v.z, (bf16_t)v.w};
    reinterpret_cast<bf16x4*>(out)[i] = o;
  }
}

// ---------------- generic bf16 GEMM: C[M,N] = A[M,K] * Bw[N,K]^T ----------------
// EPI 0: f32 row-major store to Cf (ldc=N), guarded on col<N
// EPI 1: kv scatter: col -> (h, rr); rr<128 -> Kout[b,h,s,rr]; else Vtout[b,h,rr-128,s]
template <int EPI>
__global__ __launch_bounds__(256) void k_gemm_bt(
    const bf16_t* __restrict__ A, const bf16_t* __restrict__ Bw,
    float* __restrict__ Cf, bf16_t* __restrict__ Kout, bf16_t* __restrict__ Vtout,
    int M, int N, int K) {
  __shared__ bf16x8 As[128 * 8];
  __shared__ bf16x8 Bs[128 * 8];
  const int tid = threadIdx.x;
  const int lane = tid & 63;
  const int wave = tid >> 6;
  const int wm = (wave >> 1) * 64, wn = (wave & 1) * 64;
  const int m0 = blockIdx.y * 128, n0 = blockIdx.x * 128;
  const int l15 = lane & 15, l4 = lane >> 4;

  const f32x4 Z4 = {0.f, 0.f, 0.f, 0.f};
  f32x4 acc[4][4];
#pragma unroll
  for (int i = 0; i < 4; ++i)
#pragma unroll
    for (int j = 0; j < 4; ++j) acc[i][j] = Z4;

  for (int k0 = 0; k0 < K; k0 += 64) {
    __syncthreads();
#pragma unroll
    for (int i = 0; i < 4; ++i) {
      int c = tid + i * 256;
      int row = c >> 3, kc = c & 7;
      As[row * 8 + (kc ^ (row & 7))] =
          reinterpret_cast<const bf16x8*>(A + (size_t)(m0 + row) * K + k0)[kc];
      int rn = n0 + row;
      bf16x8 bv = {(bf16_t)0.f, (bf16_t)0.f, (bf16_t)0.f, (bf16_t)0.f,
                   (bf16_t)0.f, (bf16_t)0.f, (bf16_t)0.f, (bf16_t)0.f};
      if (rn < N) bv = reinterpret_cast<const bf16x8*>(Bw + (size_t)rn * K + k0)[kc];
      Bs[row * 8 + (kc ^ (row & 7))] = bv;
    }
    __syncthreads();
#pragma unroll
    for (int ks = 0; ks < 2; ++ks) {
      bf16x8 af[4], bfr[4];
#pragma unroll
      for (int f = 0; f < 4; ++f) {
        int ar = wm + f * 16 + l15;
        int kc = ks * 4 + l4;
        af[f] = As[ar * 8 + (kc ^ (ar & 7))];
        int br = wn + f * 16 + l15;
        bfr[f] = Bs[br * 8 + (kc ^ (br & 7))];
      }
#pragma unroll
      for (int fi = 0; fi < 4; ++fi)
#pragma unroll
        for (int fj = 0; fj < 4; ++fj)
          acc[fi][fj] = __builtin_amdgcn_mfma_f32_16x16x32_bf16(af[fi], bfr[fj], acc[fi][fj], 0, 0, 0);
    }
  }

#pragma unroll
  for (int fi = 0; fi < 4; ++fi) {
#pragma unroll
    for (int fj = 0; fj < 4; ++fj) {
      int col = n0 + wn + fj * 16 + l15;
#pragma unroll
      for (int r = 0; r < 4; ++r) {
        int row = m0 + wm + fi * 16 + l4 * 4 + r;
        float v = acc[fi][fj][r];
        if (EPI == 0) {
          if (col < N) Cf[(size_t)row * N + col] = v;
        } else {
          int h = col >> 8, rr = col & 255;
          int b = row >> 11, s = row & 2047;
          if (rr < DNOPE)
            Kout[(((size_t)(b * NH + h)) * NS + s) * QKD + rr] = (bf16_t)v;
          else
            Vtout[(((size_t)(b * NH + h)) * DVDIM + (rr - DNOPE)) * NS + s] = (bf16_t)v;
        }
      }
    }
  }
}

// ---------------- RMS norm over rows (f32 in, bf16 out) ----------------
template <int COLS>
__global__ __launch_bounds__(256) void k_rmsnorm(const float* __restrict__ in,
                                                 const float* __restrict__ w,
                                                 bf16_t* __restrict__ out) {
  int row = blockIdx.x;
  const float* rp = in + (size_t)row * COLS;
  float ss = 0.f;
  for (int c = threadIdx.x * 4; c < COLS; c += 1024) {
    float4 v = *reinterpret_cast<const float4*>(rp + c);
    ss += v.x * v.x + v.y * v.y + v.z * v.z + v.w * v.w;
  }
#pragma unroll
  for (int m = 32; m; m >>= 1) ss += __shfl_xor(ss, m);
  __shared__ float red[4];
  if ((threadIdx.x & 63) == 0) red[threadIdx.x >> 6] = ss;
  __syncthreads();
  float tot = red[0] + red[1] + red[2] + red[3];
  float rs = rsqrtf(tot / (float)COLS + 1e-6f);
  for (int c = threadIdx.x * 4; c < COLS; c += 1024) {
    float4 v = *reinterpret_cast<const float4*>(rp + c);
    bf16x4 o = {(bf16_t)(v.x * rs * w[c]), (bf16_t)(v.y * rs * w[c + 1]),
                (bf16_t)(v.z * rs * w[c + 2]), (bf16_t)(v.w * rs * w[c + 3])};
    *reinterpret_cast<bf16x4*>(out + (size_t)row * COLS + c) = o;
  }
}

// ---------------- RoPE on q + pack to [B*H, S, 192] bf16 ----------------
__global__ void k_rope_q(const float* __restrict__ q, const float* __restrict__ fc,
                         const float* __restrict__ fs, bf16_t* __restrict__ Qb) {
  int idx = blockIdx.x * blockDim.x + threadIdx.x;
  const int total = NB * NS * NH * (QKD / 2);
  if (idx >= total) return;
  int p = idx % 96;
  int t = idx / 96;
  int h = t & 15;
  int bs = t >> 4;
  int b = bs >> 11, s = bs & 2047;
  const float* qp = q + (size_t)bs * (NH * QKD) + h * QKD;
  size_t ob = ((size_t)(b * NH + h) * NS + s) * QKD;
  int d = p * 2;
  float x0 = qp[d], x1 = qp[d + 1];
  if (d >= DNOPE) {
    int pp = (d - DNOPE) >> 1;
    float c = fc[s * 32 + pp], si = fs[s * 32 + pp];
    float yr = x0 * c - x1 * si, yi = x0 * si + x1 * c;
    x0 = yr;
    x1 = yi;
  }
  Qb[ob + d] = (bf16_t)x0;
  Qb[ob + d + 1] = (bf16_t)x1;
}

// ---------------- kv post: RMS norm 512 -> bf16, RoPE k_pe -> broadcast to K ----------------
__global__ __launch_bounds__(256) void k_kv_post(const float* __restrict__ kvf,
                                                 const float* __restrict__ w,
                                                 const float* __restrict__ fc,
                                                 const float* __restrict__ fs,
                                                 bf16_t* __restrict__ kvn,
                                                 bf16_t* __restrict__ Kb) {
  int row = blockIdx.x;  // token
  const float* rp = kvf + (size_t)row * (KVLORA + DROPE);
  float ss = 0.f;
  float4 v = {0.f, 0.f, 0.f, 0.f};
  if (threadIdx.x < 128) {
    v = reinterpret_cast<const float4*>(rp)[threadIdx.x];
    ss = v.x * v.x + v.y * v.y + v.z * v.z + v.w * v.w;
  }
#pragma unroll
  for (int m = 32; m; m >>= 1) ss += __shfl_xor(ss, m);
  __shared__ float red[4];
  if ((threadIdx.x & 63) == 0) red[threadIdx.x >> 6] = ss;
  __syncthreads();
  float tot = red[0] + red[1] + red[2] + red[3];
  float rs = rsqrtf(tot / (float)KVLORA + 1e-6f);
  if (threadIdx.x < 128) {
    int c = threadIdx.x * 4;
    bf16x4 o = {(bf16_t)(v.x * rs * w[c]), (bf16_t)(v.y * rs * w[c + 1]),
                (bf16_t)(v.z * rs * w[c + 2]), (bf16_t)(v.w * rs * w[c + 3])};
    *reinterpret_cast<bf16x4*>(kvn + (size_t)row * KVLORA + c) = o;
  }
  int b = row >> 11, s = row & 2047;
  if (threadIdx.x < 32) {
    int p = threadIdx.x;
    float x0 = rp[KVLORA + 2 * p], x1 = rp[KVLORA + 2 * p + 1];
    float c = fc[s * 32 + p], si = fs[s * 32 + p];
    float yr = x0 * c - x1 * si, yi = x0 * si + x1 * c;
    bf16_t br = (bf16_t)yr, bi = (bf16_t)yi;
    for (int h = 0; h < NH; ++h) {
      size_t ob = ((size_t)(b * NH + h) * NS + s) * QKD + DNOPE;
      Kb[ob + 2 * p] = br;
      Kb[ob + 2 * p + 1] = bi;
    }
  }
}

// ---------------- flash attention (causal), Q/K [B*H,S,192], Vt [B*H,128,S] ----------------
__global__ __launch_bounds__(256) void k_attn(const bf16_t* __restrict__ Qb,
                                              const bf16_t* __restrict__ Kb,
                                              const bf16_t* __restrict__ Vtb,
                                              bf16_t* __restrict__ Ao) {
  __shared__ bf16x8 Ks[64 * 24];
  __shared__ bf16x8 Vs[128 * 8];
  __shared__ bf16x8 Ps[4 * 16 * 8];
  const int bh = blockIdx.y;
  const int b = bh >> 4, h = bh & 15;
  const int qt = blockIdx.x, q0 = qt * 64;
  const int tid = threadIdx.x;
  const int lane = tid & 63, wave = tid >> 6;
  const int l15 = lane & 15, l4 = lane >> 4;

  bf16x8 qf[6];
  {
    const bf16_t* qrow = Qb + ((size_t)bh * NS + q0 + wave * 16 + l15) * QKD;
#pragma unroll
    for (int kc = 0; kc < 6; ++kc)
      qf[kc] = reinterpret_cast<const bf16x8*>(qrow)[kc * 4 + l4];
  }

  const f32x4 Z4 = {0.f, 0.f, 0.f, 0.f};
  f32x4 oacc[8];
#pragma unroll
  for (int i = 0; i < 8; ++i) oacc[i] = Z4;
  float mrun[4], lrun[4];
#pragma unroll
  for (int r = 0; r < 4; ++r) {
    mrun[r] = -1e30f;
    lrun[r] = 0.f;
  }
  const float scale = 0.07216878364870323f;  // 1/sqrt(192)

  bf16_t* Pw = reinterpret_cast<bf16_t*>(&Ps[wave * 128]);

  for (int kt = 0; kt <= qt; ++kt) {
    const int kv0 = kt * 64;
    __syncthreads();
#pragma unroll
    for (int i = 0; i < 6; ++i) {
      int c = tid + i * 256;
      int row = c / 24, kc = c - row * 24;
      Ks[row * 24 + ((kc & ~7) | ((kc ^ row) & 7))] =
          reinterpret_cast<const bf16x8*>(Kb + ((size_t)bh * NS + kv0 + row) * QKD)[kc];
    }
#pragma unroll
    for (int i = 0; i < 4; ++i) {
      int c = tid + i * 256;
      int row = c >> 3, kc = c & 7;
      Vs[row * 8 + (kc ^ (row & 7))] =
          reinterpret_cast<const bf16x8*>(Vtb + ((size_t)bh * DVDIM + row) * NS + kv0)[kc];
    }
    __syncthreads();

    f32x4 sacc[4];
#pragma unroll
    for (int sub = 0; sub < 4; ++sub) {
      sacc[sub] = Z4;
#pragma unroll
      for (int ksc = 0; ksc < 6; ++ksc) {
        int row = sub * 16 + l15;
        int kc = ksc * 4 + l4;
        bf16x8 kf = Ks[row * 24 + ((kc & ~7) | ((kc ^ row) & 7))];
        sacc[sub] = __builtin_amdgcn_mfma_f32_16x16x32_bf16(qf[ksc], kf, sacc[sub], 0, 0, 0);
      }
    }

    float sbuf[4][4];
    float mloc[4] = {-3e30f, -3e30f, -3e30f, -3e30f};
#pragma unroll
    for (int sub = 0; sub < 4; ++sub) {
      int colg = kv0 + sub * 16 + l15;
#pragma unroll
      for (int r = 0; r < 4; ++r) {
        int rowg = q0 + wave * 16 + l4 * 4 + r;
        float s = sacc[sub][r] * scale;
        if (colg > rowg) s = -1e30f;
        sbuf[sub][r] = s;
        mloc[r] = fmaxf(mloc[r], s);
      }
    }
#pragma unroll
    for (int m = 1; m < 16; m <<= 1)
#pragma unroll
      for (int r = 0; r < 4; ++r) mloc[r] = fmaxf(mloc[r], __shfl_xor(mloc[r], m));

    float fac[4], rsum[4];
#pragma unroll
    for (int r = 0; r < 4; ++r) {
      float mn = fmaxf(mrun[r], mloc[r]);
      fac[r] = __expf(mrun[r] - mn);
      mrun[r] = mn;
      lrun[r] *= fac[r];
      rsum[r] = 0.f;
    }
#pragma unroll
    for (int dc = 0; dc < 8; ++dc)
#pragma unroll
      for (int r = 0; r < 4; ++r) oacc[dc][r] *= fac[r];

#pragma unroll
    for (int sub = 0; sub < 4; ++sub) {
#pragma unroll
      for (int r = 0; r < 4; ++r) {
        float p = __expf(sbuf[sub][r] - mrun[r]);
        rsum[r] += p;
        int prow = l4 * 4 + r;
        int pcol = sub * 16 + l15;
        int chunk = pcol >> 3;
        Pw[prow * 64 + ((chunk ^ (prow & 7)) << 3) + (pcol & 7)] = (bf16_t)p;
      }
    }
#pragma unroll
    for (int m = 1; m < 16; m <<= 1)
#pragma unroll
      for (int r = 0; r < 4; ++r) rsum[r] += __shfl_xor(rsum[r], m);
#pragma unroll
    for (int r = 0; r < 4; ++r) lrun[r] += rsum[r];

#pragma unroll
    for (int ks = 0; ks < 2; ++ks) {
      int kc = ks * 4 + l4;
      bf16x8 pa = Ps[wave * 128 + l15 * 8 + (kc ^ (l15 & 7))];
#pragma unroll
      for (int dc = 0; dc < 8; ++dc) {
        int vrow = dc * 16 + l15;
        bf16x8 vf = Vs[vrow * 8 + (kc ^ (vrow & 7))];
        oacc[dc] = __builtin_amdgcn_mfma_f32_16x16x32_bf16(pa, vf, oacc[dc], 0, 0, 0);
      }
    }
  }

#pragma unroll
  for (int dc = 0; dc < 8; ++dc) {
    int dv = dc * 16 + l15;
#pragma unroll
    for (int r = 0; r < 4; ++r) {
      int rowg = q0 + wave * 16 + l4 * 4 + r;
      float v = oacc[dc][r] / lrun[r];
      Ao[((size_t)(b * NS + rowg)) * (NH * DVDIM) + h * DVDIM + dv] = (bf16_t)v;
    }
  }
}

// ---------------- launch ----------------
extern "C" void kernel_launch(void* const* d_in, const int* in_sizes, int n_in,
                              void* d_out, int out_size, void* d_ws, size_t ws_size,
                              hipStream_t stream) {
  (void)in_sizes; (void)n_in; (void)out_size; (void)ws_size;
  const float* x = (const float*)d_in[0];
  const float* fcos = (const float*)d_in[1];
  const float* fsin = (const float*)d_in[2];
  // d_in[3] = mask (unused; causal computed inline)
  const float* wq_a = (const float*)d_in[4];
  const float* q_norm_w = (const float*)d_in[5];
  const float* wq_b = (const float*)d_in[6];
  const float* wkv_a = (const float*)d_in[7];
  const float* kv_norm_w = (const float*)d_in[8];
  const float* wkv_b = (const float*)d_in[9];
  const float* wo = (const float*)d_in[10];
  float* out = (float*)d_out;

  char* p = (char*)d_ws;
  bf16_t* x_bf = (bf16_t*)(p);                    // 16,777,216
  bf16_t* wqa_bf = (bf16_t*)(p + 16777216);       //  6,291,456
  bf16_t* wqb_bf = (bf16_t*)(p + 23068672);       //  9,437,184
  bf16_t* wkva_bf = (bf16_t*)(p + 32505856);      //  2,359,296
  bf16_t* wkvb_bf = (bf16_t*)(p + 34865152);      //  4,194,304
  bf16_t* wo_bf = (bf16_t*)(p + 39059456);        //  8,388,608
  float* qa_f32 = (float*)(p + 47448064);         // 25,165,824 (dead after rmsnorm)
  bf16_t* Kb = (bf16_t*)(p + 47448064);           // 25,165,824 (union with qa_f32)
  bf16_t* qan_bf = (bf16_t*)(p + 72613888);       // 12,582,912
  bf16_t* Qb = (bf16_t*)(p + 85196800);           // 25,165,824
  char* r2 = p + 110362624;                       // 50,331,648 region
  float* q_f32 = (float*)(r2);                    // dead after rope_q
  float* kvf_f32 = (float*)(r2);                  //  9,437,184
  bf16_t* kvn_bf = (bf16_t*)(r2 + 9437184);       //  4,194,304
  bf16_t* Vtb = (bf16_t*)(r2 + 13631488);         // 16,777,216
  bf16_t* attn_bf = (bf16_t*)(r2 + 30408704);     // 16,777,216
  // total ws = 157,548,544 bytes

  auto cvt = [&](const float* src, bf16_t* dst, size_t n) {
    int n4 = (int)(n / 4);
    int grid = (n4 + 255) / 256;
    k_cvt<<<grid, 256, 0, stream>>>(src, dst, n4);
  };
  cvt(x, x_bf, (size_t)NB * NS * ND);
  cvt(wq_a, wqa_bf, (size_t)QLORA * ND);
  cvt(wq_b, wqb_bf, (size_t)(NH * QKD) * QLORA);
  cvt(wkv_a, wkva_bf, (size_t)(KVLORA + DROPE) * ND);
  cvt(wkv_b, wkvb_bf, (size_t)(NH * (DNOPE + DVDIM)) * KVLORA);
  cvt(wo, wo_bf, (size_t)ND * (NH * DVDIM));

  // q_a = x @ wq_a^T        [4096,1536]
  k_gemm_bt<0><<<dim3(12, 32), 256, 0, stream>>>(x_bf, wqa_bf, qa_f32, nullptr, nullptr,
                                                 NB * NS, QLORA, ND);
  k_rmsnorm<QLORA><<<NB * NS, 256, 0, stream>>>(qa_f32, q_norm_w, qan_bf);
  // q = q_a_n @ wq_b^T      [4096,3072]
  k_gemm_bt<0><<<dim3(24, 32), 256, 0, stream>>>(qan_bf, wqb_bf, q_f32, nullptr, nullptr,
                                                 NB * NS, NH * QKD, QLORA);
  {
    int total = NB * NS * NH * (QKD / 2);
    k_rope_q<<<(total + 255) / 256, 256, 0, stream>>>(q_f32, fcos, fsin, Qb);
  }
  // kv_full = x @ wkv_a^T   [4096,576]
  k_gemm_bt<0><<<dim3(5, 32), 256, 0, stream>>>(x_bf, wkva_bf, kvf_f32, nullptr, nullptr,
                                                NB * NS, KVLORA + DROPE, ND);
  k_kv_post<<<NB * NS, 256, 0, stream>>>(kvf_f32, kv_norm_w, fcos, fsin, kvn_bf, Kb);
  // kv_b = kv_n @ wkv_b^T   [4096,4096] -> scatter K (nope) + Vt
  k_gemm_bt<1><<<dim3(32, 32), 256, 0, stream>>>(kvn_bf, wkvb_bf, nullptr, Kb, Vtb,
                                                 NB * NS, NH * (DNOPE + DVDIM), KVLORA);
  // attention
  k_attn<<<dim3(NS / 64, NB * NH), 256, 0, stream>>>(Qb, Kb, Vtb, attn_bf);
  // out = attn @ wo^T       [4096,2048]
  k_gemm_bt<0><<<dim3(16, 32), 256, 0, stream>>>(attn_bf, wo_bf, out, nullptr, nullptr,
                                                 NB * NS, ND, NH * DVDIM);
}

// Round 3
// 507.320 us; speedup vs baseline: 1.1645x; 1.1645x over previous
//
#include <hip/hip_runtime.h>
#include <hip/hip_bf16.h>

typedef __bf16 bf16_t;
typedef __bf16 bf16x8 __attribute__((ext_vector_type(8)));
typedef __bf16 bf16x4 __attribute__((ext_vector_type(4)));
typedef float  f32x4  __attribute__((ext_vector_type(4)));

#define NB 2
#define NS 2048
#define ND 2048
#define NH 16
#define QLORA 1536
#define KVLORA 512
#define DNOPE 128
#define DROPE 64
#define DVDIM 128
#define QKD 192

// 1/sqrt(192) * log2(e): Q is pre-scaled by this so QK^T lands in exp2 domain.
#define QSCALE 0.10411754f

#if __has_builtin(__builtin_amdgcn_exp2f)
#define EXP2F(x) __builtin_amdgcn_exp2f(x)
#else
#define EXP2F(x) __expf((x) * 0.69314718056f)
#endif
#if __has_builtin(__builtin_amdgcn_rcpf)
#define RCPF(x) __builtin_amdgcn_rcpf(x)
#else
#define RCPF(x) (1.0f / (x))
#endif

// ---------------- f32 -> bf16 convert (vectorized) ----------------
__global__ void k_cvt(const float* __restrict__ in, bf16_t* __restrict__ out, int n4) {
  int i = blockIdx.x * blockDim.x + threadIdx.x;
  int stride = gridDim.x * blockDim.x;
  for (; i < n4; i += stride) {
    float4 v = reinterpret_cast<const float4*>(in)[i];
    bf16x4 o = {(bf16_t)v.x, (bf16_t)v.y, (bf16_t)v.z, (bf16_t)v.w};
    reinterpret_cast<bf16x4*>(out)[i] = o;
  }
}

// ---------------- generic bf16 GEMM: C[M,N] = A[M,K] * Bw[N,K]^T ----------------
template <int EPI>
__global__ __launch_bounds__(256) void k_gemm_bt(
    const bf16_t* __restrict__ A, const bf16_t* __restrict__ Bw,
    float* __restrict__ Cf, bf16_t* __restrict__ Kout, bf16_t* __restrict__ Vtout,
    int M, int N, int K) {
  __shared__ bf16x8 As[128 * 8];
  __shared__ bf16x8 Bs[128 * 8];
  const int tid = threadIdx.x;
  const int lane = tid & 63;
  const int wave = tid >> 6;
  const int wm = (wave >> 1) * 64, wn = (wave & 1) * 64;
  const int m0 = blockIdx.y * 128, n0 = blockIdx.x * 128;
  const int l15 = lane & 15, l4 = lane >> 4;

  const f32x4 Z4 = {0.f, 0.f, 0.f, 0.f};
  f32x4 acc[4][4];
#pragma unroll
  for (int i = 0; i < 4; ++i)
#pragma unroll
    for (int j = 0; j < 4; ++j) acc[i][j] = Z4;

  for (int k0 = 0; k0 < K; k0 += 64) {
    __syncthreads();
#pragma unroll
    for (int i = 0; i < 4; ++i) {
      int c = tid + i * 256;
      int row = c >> 3, kc = c & 7;
      As[row * 8 + (kc ^ (row & 7))] =
          reinterpret_cast<const bf16x8*>(A + (size_t)(m0 + row) * K + k0)[kc];
      int rn = n0 + row;
      bf16x8 bv = {(bf16_t)0.f, (bf16_t)0.f, (bf16_t)0.f, (bf16_t)0.f,
                   (bf16_t)0.f, (bf16_t)0.f, (bf16_t)0.f, (bf16_t)0.f};
      if (rn < N) bv = reinterpret_cast<const bf16x8*>(Bw + (size_t)rn * K + k0)[kc];
      Bs[row * 8 + (kc ^ (row & 7))] = bv;
    }
    __syncthreads();
#pragma unroll
    for (int ks = 0; ks < 2; ++ks) {
      bf16x8 af[4], bfr[4];
#pragma unroll
      for (int f = 0; f < 4; ++f) {
        int ar = wm + f * 16 + l15;
        int kc = ks * 4 + l4;
        af[f] = As[ar * 8 + (kc ^ (ar & 7))];
        int br = wn + f * 16 + l15;
        bfr[f] = Bs[br * 8 + (kc ^ (br & 7))];
      }
#pragma unroll
      for (int fi = 0; fi < 4; ++fi)
#pragma unroll
        for (int fj = 0; fj < 4; ++fj)
          acc[fi][fj] = __builtin_amdgcn_mfma_f32_16x16x32_bf16(af[fi], bfr[fj], acc[fi][fj], 0, 0, 0);
    }
  }

#pragma unroll
  for (int fi = 0; fi < 4; ++fi) {
#pragma unroll
    for (int fj = 0; fj < 4; ++fj) {
      int col = n0 + wn + fj * 16 + l15;
#pragma unroll
      for (int r = 0; r < 4; ++r) {
        int row = m0 + wm + fi * 16 + l4 * 4 + r;
        float v = acc[fi][fj][r];
        if (EPI == 0) {
          if (col < N) Cf[(size_t)row * N + col] = v;
        } else {
          int h = col >> 8, rr = col & 255;
          int b = row >> 11, s = row & 2047;
          if (rr < DNOPE)
            Kout[(((size_t)(b * NH + h)) * NS + s) * QKD + rr] = (bf16_t)v;
          else
            Vtout[(((size_t)(b * NH + h)) * DVDIM + (rr - DNOPE)) * NS + s] = (bf16_t)v;
        }
      }
    }
  }
}

// ---------------- RMS norm over rows (f32 in, bf16 out) ----------------
template <int COLS>
__global__ __launch_bounds__(256) void k_rmsnorm(const float* __restrict__ in,
                                                 const float* __restrict__ w,
                                                 bf16_t* __restrict__ out) {
  int row = blockIdx.x;
  const float* rp = in + (size_t)row * COLS;
  float ss = 0.f;
  for (int c = threadIdx.x * 4; c < COLS; c += 1024) {
    float4 v = *reinterpret_cast<const float4*>(rp + c);
    ss += v.x * v.x + v.y * v.y + v.z * v.z + v.w * v.w;
  }
#pragma unroll
  for (int m = 32; m; m >>= 1) ss += __shfl_xor(ss, m);
  __shared__ float red[4];
  if ((threadIdx.x & 63) == 0) red[threadIdx.x >> 6] = ss;
  __syncthreads();
  float tot = red[0] + red[1] + red[2] + red[3];
  float rs = rsqrtf(tot / (float)COLS + 1e-6f);
  for (int c = threadIdx.x * 4; c < COLS; c += 1024) {
    float4 v = *reinterpret_cast<const float4*>(rp + c);
    bf16x4 o = {(bf16_t)(v.x * rs * w[c]), (bf16_t)(v.y * rs * w[c + 1]),
                (bf16_t)(v.z * rs * w[c + 2]), (bf16_t)(v.w * rs * w[c + 3])};
    *reinterpret_cast<bf16x4*>(out + (size_t)row * COLS + c) = o;
  }
}

// ---------------- RoPE on q + pack to [B*H, S, 192] bf16, pre-scaled ----------------
__global__ void k_rope_q(const float* __restrict__ q, const float* __restrict__ fc,
                         const float* __restrict__ fs, bf16_t* __restrict__ Qb) {
  int idx = blockIdx.x * blockDim.x + threadIdx.x;
  const int total = NB * NS * NH * (QKD / 2);
  if (idx >= total) return;
  int p = idx % 96;
  int t = idx / 96;
  int h = t & 15;
  int bs = t >> 4;
  int b = bs >> 11, s = bs & 2047;
  const float* qp = q + (size_t)bs * (NH * QKD) + h * QKD;
  size_t ob = ((size_t)(b * NH + h) * NS + s) * QKD;
  int d = p * 2;
  float x0 = qp[d], x1 = qp[d + 1];
  if (d >= DNOPE) {
    int pp = (d - DNOPE) >> 1;
    float c = fc[s * 32 + pp], si = fs[s * 32 + pp];
    float yr = x0 * c - x1 * si, yi = x0 * si + x1 * c;
    x0 = yr;
    x1 = yi;
  }
  Qb[ob + d] = (bf16_t)(x0 * QSCALE);
  Qb[ob + d + 1] = (bf16_t)(x1 * QSCALE);
}

// ---------------- kv post: RMS norm 512 -> bf16, RoPE k_pe -> broadcast to K ----------------
__global__ __launch_bounds__(256) void k_kv_post(const float* __restrict__ kvf,
                                                 const float* __restrict__ w,
                                                 const float* __restrict__ fc,
                                                 const float* __restrict__ fs,
                                                 bf16_t* __restrict__ kvn,
                                                 bf16_t* __restrict__ Kb) {
  int row = blockIdx.x;  // token
  const float* rp = kvf + (size_t)row * (KVLORA + DROPE);
  float ss = 0.f;
  float4 v = {0.f, 0.f, 0.f, 0.f};
  if (threadIdx.x < 128) {
    v = reinterpret_cast<const float4*>(rp)[threadIdx.x];
    ss = v.x * v.x + v.y * v.y + v.z * v.z + v.w * v.w;
  }
#pragma unroll
  for (int m = 32; m; m >>= 1) ss += __shfl_xor(ss, m);
  __shared__ float red[4];
  if ((threadIdx.x & 63) == 0) red[threadIdx.x >> 6] = ss;
  __syncthreads();
  float tot = red[0] + red[1] + red[2] + red[3];
  float rs = rsqrtf(tot / (float)KVLORA + 1e-6f);
  if (threadIdx.x < 128) {
    int c = threadIdx.x * 4;
    bf16x4 o = {(bf16_t)(v.x * rs * w[c]), (bf16_t)(v.y * rs * w[c + 1]),
                (bf16_t)(v.z * rs * w[c + 2]), (bf16_t)(v.w * rs * w[c + 3])};
    *reinterpret_cast<bf16x4*>(kvn + (size_t)row * KVLORA + c) = o;
  }
  int b = row >> 11, s = row & 2047;
  if (threadIdx.x < 32) {
    int p = threadIdx.x;
    float x0 = rp[KVLORA + 2 * p], x1 = rp[KVLORA + 2 * p + 1];
    float c = fc[s * 32 + p], si = fs[s * 32 + p];
    float yr = x0 * c - x1 * si, yi = x0 * si + x1 * c;
    bf16_t br = (bf16_t)yr, bi = (bf16_t)yi;
    for (int h = 0; h < NH; ++h) {
      size_t ob = ((size_t)(b * NH + h) * NS + s) * QKD + DNOPE;
      Kb[ob + 2 * p] = br;
      Kb[ob + 2 * p + 1] = bi;
    }
  }
}

// ---------------- flash attention tile (MASK only on diagonal) ----------------
template <bool MASK>
__device__ __forceinline__ void attn_tile(
    int kv0, size_t bhNS, size_t bhDV,
    const bf16_t* __restrict__ Kb, const bf16_t* __restrict__ Vtb,
    bf16x8* Ks, bf16x8* Vs, bf16x8* Ps, bf16_t* Pw,
    const bf16x8 (&qf)[6], f32x4 (&oacc)[8], float (&mrun)[4], float (&lrun)[4],
    int tid, int wave, int l15, int l4, int qrow) {
  const f32x4 Z4 = {0.f, 0.f, 0.f, 0.f};
  __syncthreads();
#pragma unroll
  for (int i = 0; i < 6; ++i) {
    int c = tid + i * 256;
    int row = c / 24, kc = c - row * 24;
    Ks[row * 24 + ((kc & ~7) | ((kc ^ row) & 7))] =
        reinterpret_cast<const bf16x8*>(Kb + (bhNS + kv0 + row) * QKD)[kc];
  }
#pragma unroll
  for (int i = 0; i < 4; ++i) {
    int c = tid + i * 256;
    int row = c >> 3, kc = c & 7;
    Vs[row * 8 + (kc ^ (row & 7))] =
        reinterpret_cast<const bf16x8*>(Vtb + (bhDV + row) * NS + kv0)[kc];
  }
  __syncthreads();

  f32x4 sacc[4];
#pragma unroll
  for (int sub = 0; sub < 4; ++sub) {
    sacc[sub] = Z4;
#pragma unroll
    for (int ksc = 0; ksc < 6; ++ksc) {
      int row = sub * 16 + l15;
      int kc = ksc * 4 + l4;
      bf16x8 kf = Ks[row * 24 + ((kc & ~7) | ((kc ^ row) & 7))];
      sacc[sub] = __builtin_amdgcn_mfma_f32_16x16x32_bf16(qf[ksc], kf, sacc[sub], 0, 0, 0);
    }
  }

  float sbuf[4][4];
  float mloc[4] = {-3e38f, -3e38f, -3e38f, -3e38f};
#pragma unroll
  for (int sub = 0; sub < 4; ++sub) {
#pragma unroll
    for (int r = 0; r < 4; ++r) {
      float s = sacc[sub][r];
      if (MASK) {
        int colg = kv0 + sub * 16 + l15;
        int rowg = qrow + l4 * 4 + r;
        if (colg > rowg) s = -3e38f;
      }
      sbuf[sub][r] = s;
      mloc[r] = fmaxf(mloc[r], s);
    }
  }
#pragma unroll
  for (int m = 1; m < 16; m <<= 1)
#pragma unroll
    for (int r = 0; r < 4; ++r) mloc[r] = fmaxf(mloc[r], __shfl_xor(mloc[r], m));

  // exact skip-rescale: if no row's max grew (all 64 lanes), fac==1 -> skip
  float d0 = fmaxf(fmaxf(mloc[0] - mrun[0], mloc[1] - mrun[1]),
                   fmaxf(mloc[2] - mrun[2], mloc[3] - mrun[3]));
  if (!__all(d0 <= 0.f)) {
#pragma unroll
    for (int r = 0; r < 4; ++r) {
      float mn = fmaxf(mrun[r], mloc[r]);
      float fac = EXP2F(mrun[r] - mn);
      mrun[r] = mn;
      lrun[r] *= fac;
#pragma unroll
      for (int dc = 0; dc < 8; ++dc) oacc[dc][r] *= fac;
    }
  }

  float rsum[4] = {0.f, 0.f, 0.f, 0.f};
#pragma unroll
  for (int sub = 0; sub < 4; ++sub) {
#pragma unroll
    for (int r = 0; r < 4; ++r) {
      float p = EXP2F(sbuf[sub][r] - mrun[r]);
      rsum[r] += p;
      int prow = l4 * 4 + r;
      int pcol = sub * 16 + l15;
      Pw[prow * 64 + (((pcol >> 3) ^ (prow & 7)) << 3) + (pcol & 7)] = (bf16_t)p;
    }
  }
#pragma unroll
  for (int m = 1; m < 16; m <<= 1)
#pragma unroll
    for (int r = 0; r < 4; ++r) rsum[r] += __shfl_xor(rsum[r], m);
#pragma unroll
  for (int r = 0; r < 4; ++r) lrun[r] += rsum[r];

#pragma unroll
  for (int ks = 0; ks < 2; ++ks) {
    int kc = ks * 4 + l4;
    bf16x8 pa = Ps[(Pw - reinterpret_cast<bf16_t*>(Ps)) / 128 * 128 / 128 * 128 + 0];  // placeholder avoided below
    (void)pa;
    bf16x8 pa2 = *reinterpret_cast<bf16x8*>(Pw + l15 * 8 * 8 / 8 * 8 * 0);  // not used
    (void)pa2;
    bf16x8 paf = reinterpret_cast<bf16x8*>(Pw)[l15 * 8 + (kc ^ (l15 & 7))];
#pragma unroll
    for (int dc = 0; dc < 8; ++dc) {
      int vrow = dc * 16 + l15;
      bf16x8 vf = Vs[vrow * 8 + (kc ^ (vrow & 7))];
      oacc[dc] = __builtin_amdgcn_mfma_f32_16x16x32_bf16(paf, vf, oacc[dc], 0, 0, 0);
    }
  }
}

// ---------------- flash attention (causal), paired q-tiles for load balance ----------------
__global__ __launch_bounds__(256) void k_attn(const bf16_t* __restrict__ Qb,
                                              const bf16_t* __restrict__ Kb,
                                              const bf16_t* __restrict__ Vtb,
                                              bf16_t* __restrict__ Ao) {
  __shared__ bf16x8 Ks[64 * 24];
  __shared__ bf16x8 Vs[128 * 8];
  __shared__ bf16x8 Ps[4 * 16 * 8];
  const int bh = blockIdx.y;
  const int b = bh >> 4, h = bh & 15;
  const int tid = threadIdx.x;
  const int lane = tid & 63, wave = tid >> 6;
  const int l15 = lane & 15, l4 = lane >> 4;
  const size_t bhNS = (size_t)bh * NS;
  const size_t bhDV = (size_t)bh * DVDIM;
  bf16_t* Pw = reinterpret_cast<bf16_t*>(&Ps[wave * 128]);

#pragma unroll 1
  for (int phase = 0; phase < 2; ++phase) {
    const int qt = (phase == 0) ? (31 - (int)blockIdx.x) : (int)blockIdx.x;
    const int q0 = qt * 64;
    const int qrow = q0 + wave * 16;

    bf16x8 qf[6];
    {
      const bf16_t* qrp = Qb + (bhNS + qrow + l15) * QKD;
#pragma unroll
      for (int kc = 0; kc < 6; ++kc)
        qf[kc] = reinterpret_cast<const bf16x8*>(qrp)[kc * 4 + l4];
    }

    const f32x4 Z4 = {0.f, 0.f, 0.f, 0.f};
    f32x4 oacc[8];
#pragma unroll
    for (int i = 0; i < 8; ++i) oacc[i] = Z4;
    float mrun[4], lrun[4];
#pragma unroll
    for (int r = 0; r < 4; ++r) {
      mrun[r] = -3e38f;
      lrun[r] = 0.f;
    }

    for (int kt = 0; kt < qt; ++kt)
      attn_tile<false>(kt * 64, bhNS, bhDV, Kb, Vtb, Ks, Vs, Ps, Pw, qf, oacc, mrun, lrun,
                       tid, wave, l15, l4, qrow);
    attn_tile<true>(q0, bhNS, bhDV, Kb, Vtb, Ks, Vs, Ps, Pw, qf, oacc, mrun, lrun,
                    tid, wave, l15, l4, qrow);

#pragma unroll
    for (int r = 0; r < 4; ++r) lrun[r] = RCPF(lrun[r]);
#pragma unroll
    for (int dc = 0; dc < 8; ++dc) {
      int dv = dc * 16 + l15;
#pragma unroll
      for (int r = 0; r < 4; ++r) {
        int rowg = q0 + wave * 16 + l4 * 4 + r;
        float v = oacc[dc][r] * lrun[r];
        Ao[((size_t)(b * NS + rowg)) * (NH * DVDIM) + h * DVDIM + dv] = (bf16_t)v;
      }
    }
  }
}

// ---------------- launch ----------------
extern "C" void kernel_launch(void* const* d_in, const int* in_sizes, int n_in,
                              void* d_out, int out_size, void* d_ws, size_t ws_size,
                              hipStream_t stream) {
  (void)in_sizes; (void)n_in; (void)out_size; (void)ws_size;
  const float* x = (const float*)d_in[0];
  const float* fcos = (const float*)d_in[1];
  const float* fsin = (const float*)d_in[2];
  const float* wq_a = (const float*)d_in[4];
  const float* q_norm_w = (const float*)d_in[5];
  const float* wq_b = (const float*)d_in[6];
  const float* wkv_a = (const float*)d_in[7];
  const float* kv_norm_w = (const float*)d_in[8];
  const float* wkv_b = (const float*)d_in[9];
  const float* wo = (const float*)d_in[10];
  float* out = (float*)d_out;

  char* p = (char*)d_ws;
  bf16_t* x_bf = (bf16_t*)(p);
  bf16_t* wqa_bf = (bf16_t*)(p + 16777216);
  bf16_t* wqb_bf = (bf16_t*)(p + 23068672);
  bf16_t* wkva_bf = (bf16_t*)(p + 32505856);
  bf16_t* wkvb_bf = (bf16_t*)(p + 34865152);
  bf16_t* wo_bf = (bf16_t*)(p + 39059456);
  float* qa_f32 = (float*)(p + 47448064);
  bf16_t* Kb = (bf16_t*)(p + 47448064);
  bf16_t* qan_bf = (bf16_t*)(p + 72613888);
  bf16_t* Qb = (bf16_t*)(p + 85196800);
  char* r2 = p + 110362624;
  float* q_f32 = (float*)(r2);
  float* kvf_f32 = (float*)(r2);
  bf16_t* kvn_bf = (bf16_t*)(r2 + 9437184);
  bf16_t* Vtb = (bf16_t*)(r2 + 13631488);
  bf16_t* attn_bf = (bf16_t*)(r2 + 30408704);

  auto cvt = [&](const float* src, bf16_t* dst, size_t n) {
    int n4 = (int)(n / 4);
    int grid = (n4 + 255) / 256;
    k_cvt<<<grid, 256, 0, stream>>>(src, dst, n4);
  };
  cvt(x, x_bf, (size_t)NB * NS * ND);
  cvt(wq_a, wqa_bf, (size_t)QLORA * ND);
  cvt(wq_b, wqb_bf, (size_t)(NH * QKD) * QLORA);
  cvt(wkv_a, wkva_bf, (size_t)(KVLORA + DROPE) * ND);
  cvt(wkv_b, wkvb_bf, (size_t)(NH * (DNOPE + DVDIM)) * KVLORA);
  cvt(wo, wo_bf, (size_t)ND * (NH * DVDIM));

  k_gemm_bt<0><<<dim3(12, 32), 256, 0, stream>>>(x_bf, wqa_bf, qa_f32, nullptr, nullptr,
                                                 NB * NS, QLORA, ND);
  k_rmsnorm<QLORA><<<NB * NS, 256, 0, stream>>>(qa_f32, q_norm_w, qan_bf);
  k_gemm_bt<0><<<dim3(24, 32), 256, 0, stream>>>(qan_bf, wqb_bf, q_f32, nullptr, nullptr,
                                                 NB * NS, NH * QKD, QLORA);
  {
    int total = NB * NS * NH * (QKD / 2);
    k_rope_q<<<(total + 255) / 256, 256, 0, stream>>>(q_f32, fcos, fsin, Qb);
  }
  k_gemm_bt<0><<<dim3(5, 32), 256, 0, stream>>>(x_bf, wkva_bf, kvf_f32, nullptr, nullptr,
                                                NB * NS, KVLORA + DROPE, ND);
  k_kv_post<<<NB * NS, 256, 0, stream>>>(kvf_f32, kv_norm_w, fcos, fsin, kvn_bf, Kb);
  k_gemm_bt<1><<<dim3(32, 32), 256, 0, stream>>>(kvn_bf, wkvb_bf, nullptr, Kb, Vtb,
                                                 NB * NS, NH * (DNOPE + DVDIM), KVLORA);
  k_attn<<<dim3(16, NB * NH), 256, 0, stream>>>(Qb, Kb, Vtb, attn_bf);
  k_gemm_bt<0><<<dim3(16, 32), 256, 0, stream>>>(attn_bf, wo_bf, out, nullptr, nullptr,
                                                 NB * NS, ND, NH * DVDIM);
}

// Round 4
// 432.274 us; speedup vs baseline: 1.3666x; 1.1736x over previous
//
#include <hip/hip_runtime.h>
#include <hip/hip_bf16.h>

typedef __bf16 bf16_t;
typedef __bf16 bf16x8 __attribute__((ext_vector_type(8)));
typedef __bf16 bf16x4 __attribute__((ext_vector_type(4)));
typedef float  f32x4  __attribute__((ext_vector_type(4)));

#define NB 2
#define NS 2048
#define ND 2048
#define NH 16
#define QLORA 1536
#define KVLORA 512
#define DNOPE 128
#define DROPE 64
#define DVDIM 128
#define QKD 192

// 1/sqrt(192) * log2(e): Q is pre-scaled by this so QK^T lands in exp2 domain.
#define QSCALE 0.10411754f

#if __has_builtin(__builtin_amdgcn_exp2f)
#define EXP2F(x) __builtin_amdgcn_exp2f(x)
#else
#define EXP2F(x) __expf((x) * 0.69314718056f)
#endif
#if __has_builtin(__builtin_amdgcn_rcpf)
#define RCPF(x) __builtin_amdgcn_rcpf(x)
#else
#define RCPF(x) (1.0f / (x))
#endif

typedef __attribute__((address_space(3))) void as3_void;
typedef __attribute__((address_space(1))) const void as1_void;
__device__ __forceinline__ void gload16(const void* g, void* l) {
  __builtin_amdgcn_global_load_lds((as1_void*)g, (as3_void*)l, 16, 0, 0);
}

// ---------------- f32 -> bf16 convert (vectorized) ----------------
__global__ void k_cvt(const float* __restrict__ in, bf16_t* __restrict__ out, int n4) {
  int i = blockIdx.x * blockDim.x + threadIdx.x;
  int stride = gridDim.x * blockDim.x;
  for (; i < n4; i += stride) {
    float4 v = reinterpret_cast<const float4*>(in)[i];
    bf16x4 o = {(bf16_t)v.x, (bf16_t)v.y, (bf16_t)v.z, (bf16_t)v.w};
    reinterpret_cast<bf16x4*>(out)[i] = o;
  }
}

// ---------------- generic bf16 GEMM: C[M,N] = A[M,K] * Bw[N,K]^T ----------------
// Staging via global_load_lds (width 16), linear LDS [row][64]. OOB B-rows
// (N%128 != 0) over-read mapped ws memory; results discarded by epilogue guard.
template <int EPI>
__global__ __launch_bounds__(256) void k_gemm_bt(
    const bf16_t* __restrict__ A, const bf16_t* __restrict__ Bw,
    float* __restrict__ Cf, bf16_t* __restrict__ Kout, bf16_t* __restrict__ Vtout,
    int M, int N, int K) {
  __shared__ bf16_t As[128 * 64];
  __shared__ bf16_t Bs[128 * 64];
  const int tid = threadIdx.x;
  const int lane = tid & 63;
  const int wave = tid >> 6;
  const int wm = (wave >> 1) * 64, wn = (wave & 1) * 64;
  const int m0 = blockIdx.y * 128, n0 = blockIdx.x * 128;
  const int l15 = lane & 15, l4 = lane >> 4;
  const int srow = lane >> 3;        // 0..7 within chunk
  const int scol = (lane & 7) * 8;   // bf16 col offset

  const f32x4 Z4 = {0.f, 0.f, 0.f, 0.f};
  f32x4 acc[4][4];
#pragma unroll
  for (int i = 0; i < 4; ++i)
#pragma unroll
    for (int j = 0; j < 4; ++j) acc[i][j] = Z4;

  for (int k0 = 0; k0 < K; k0 += 64) {
    __syncthreads();
#pragma unroll
    for (int c = 0; c < 4; ++c) {
      int chunk = c * 4 + wave;       // 0..15, wave-uniform
      int row = chunk * 8 + srow;     // per-lane global row
      gload16(A + (size_t)(m0 + row) * K + k0 + scol, &As[chunk * 512]);
      gload16(Bw + (size_t)(n0 + row) * K + k0 + scol, &Bs[chunk * 512]);
    }
    __syncthreads();
#pragma unroll
    for (int ks = 0; ks < 2; ++ks) {
      int kc = ks * 4 + l4;
      bf16x8 af[4], bfr[4];
#pragma unroll
      for (int f = 0; f < 4; ++f) {
        af[f] = *reinterpret_cast<const bf16x8*>(&As[(wm + f * 16 + l15) * 64 + kc * 8]);
        bfr[f] = *reinterpret_cast<const bf16x8*>(&Bs[(wn + f * 16 + l15) * 64 + kc * 8]);
      }
#pragma unroll
      for (int fi = 0; fi < 4; ++fi)
#pragma unroll
        for (int fj = 0; fj < 4; ++fj)
          acc[fi][fj] = __builtin_amdgcn_mfma_f32_16x16x32_bf16(af[fi], bfr[fj], acc[fi][fj], 0, 0, 0);
    }
  }

#pragma unroll
  for (int fi = 0; fi < 4; ++fi) {
#pragma unroll
    for (int fj = 0; fj < 4; ++fj) {
      int col = n0 + wn + fj * 16 + l15;
#pragma unroll
      for (int r = 0; r < 4; ++r) {
        int row = m0 + wm + fi * 16 + l4 * 4 + r;
        float v = acc[fi][fj][r];
        if (EPI == 0) {
          if (col < N) Cf[(size_t)row * N + col] = v;
        } else {
          int h = col >> 8, rr = col & 255;
          int b = row >> 11, s = row & 2047;
          if (rr < DNOPE)
            Kout[(((size_t)(b * NH + h)) * NS + s) * QKD + rr] = (bf16_t)v;
          else
            Vtout[(((size_t)(b * NH + h)) * DVDIM + (rr - DNOPE)) * NS + s] = (bf16_t)v;
        }
      }
    }
  }
}

// ---------------- RMS norm over rows (f32 in, bf16 out) ----------------
template <int COLS>
__global__ __launch_bounds__(256) void k_rmsnorm(const float* __restrict__ in,
                                                 const float* __restrict__ w,
                                                 bf16_t* __restrict__ out) {
  int row = blockIdx.x;
  const float* rp = in + (size_t)row * COLS;
  float ss = 0.f;
  for (int c = threadIdx.x * 4; c < COLS; c += 1024) {
    float4 v = *reinterpret_cast<const float4*>(rp + c);
    ss += v.x * v.x + v.y * v.y + v.z * v.z + v.w * v.w;
  }
#pragma unroll
  for (int m = 32; m; m >>= 1) ss += __shfl_xor(ss, m);
  __shared__ float red[4];
  if ((threadIdx.x & 63) == 0) red[threadIdx.x >> 6] = ss;
  __syncthreads();
  float tot = red[0] + red[1] + red[2] + red[3];
  float rs = rsqrtf(tot / (float)COLS + 1e-6f);
  for (int c = threadIdx.x * 4; c < COLS; c += 1024) {
    float4 v = *reinterpret_cast<const float4*>(rp + c);
    bf16x4 o = {(bf16_t)(v.x * rs * w[c]), (bf16_t)(v.y * rs * w[c + 1]),
                (bf16_t)(v.z * rs * w[c + 2]), (bf16_t)(v.w * rs * w[c + 3])};
    *reinterpret_cast<bf16x4*>(out + (size_t)row * COLS + c) = o;
  }
}

// ---------------- RoPE on q + pack to [B*H, S, 192] bf16, pre-scaled ----------------
__global__ void k_rope_q(const float* __restrict__ q, const float* __restrict__ fc,
                         const float* __restrict__ fs, bf16_t* __restrict__ Qb) {
  int idx = blockIdx.x * blockDim.x + threadIdx.x;
  const int total = NB * NS * NH * (QKD / 2);
  if (idx >= total) return;
  int p = idx % 96;
  int t = idx / 96;
  int h = t & 15;
  int bs = t >> 4;
  int b = bs >> 11, s = bs & 2047;
  const float* qp = q + (size_t)bs * (NH * QKD) + h * QKD;
  size_t ob = ((size_t)(b * NH + h) * NS + s) * QKD;
  int d = p * 2;
  float x0 = qp[d], x1 = qp[d + 1];
  if (d >= DNOPE) {
    int pp = (d - DNOPE) >> 1;
    float c = fc[s * 32 + pp], si = fs[s * 32 + pp];
    float yr = x0 * c - x1 * si, yi = x0 * si + x1 * c;
    x0 = yr;
    x1 = yi;
  }
  Qb[ob + d] = (bf16_t)(x0 * QSCALE);
  Qb[ob + d + 1] = (bf16_t)(x1 * QSCALE);
}

// ---------------- kv post: RMS norm 512 -> bf16, RoPE k_pe -> broadcast to K ----------------
__global__ __launch_bounds__(256) void k_kv_post(const float* __restrict__ kvf,
                                                 const float* __restrict__ w,
                                                 const float* __restrict__ fc,
                                                 const float* __restrict__ fs,
                                                 bf16_t* __restrict__ kvn,
                                                 bf16_t* __restrict__ Kb) {
  int row = blockIdx.x;  // token
  const float* rp = kvf + (size_t)row * (KVLORA + DROPE);
  float ss = 0.f;
  float4 v = {0.f, 0.f, 0.f, 0.f};
  if (threadIdx.x < 128) {
    v = reinterpret_cast<const float4*>(rp)[threadIdx.x];
    ss = v.x * v.x + v.y * v.y + v.z * v.z + v.w * v.w;
  }
#pragma unroll
  for (int m = 32; m; m >>= 1) ss += __shfl_xor(ss, m);
  __shared__ float red[4];
  if ((threadIdx.x & 63) == 0) red[threadIdx.x >> 6] = ss;
  __syncthreads();
  float tot = red[0] + red[1] + red[2] + red[3];
  float rs = rsqrtf(tot / (float)KVLORA + 1e-6f);
  if (threadIdx.x < 128) {
    int c = threadIdx.x * 4;
    bf16x4 o = {(bf16_t)(v.x * rs * w[c]), (bf16_t)(v.y * rs * w[c + 1]),
                (bf16_t)(v.z * rs * w[c + 2]), (bf16_t)(v.w * rs * w[c + 3])};
    *reinterpret_cast<bf16x4*>(kvn + (size_t)row * KVLORA + c) = o;
  }
  int b = row >> 11, s = row & 2047;
  if (threadIdx.x < 32) {
    int p = threadIdx.x;
    float x0 = rp[KVLORA + 2 * p], x1 = rp[KVLORA + 2 * p + 1];
    float c = fc[s * 32 + p], si = fs[s * 32 + p];
    float yr = x0 * c - x1 * si, yi = x0 * si + x1 * c;
    bf16_t br = (bf16_t)yr, bi = (bf16_t)yi;
    for (int h = 0; h < NH; ++h) {
      size_t ob = ((size_t)(b * NH + h) * NS + s) * QKD + DNOPE;
      Kb[ob + 2 * p] = br;
      Kb[ob + 2 * p + 1] = bi;
    }
  }
}

// ---------------- flash attention tile (MASK only on diagonal) ----------------
template <bool MASK>
__device__ __forceinline__ void attn_tile(
    int kv0, size_t bhNS, size_t bhDV,
    const bf16_t* __restrict__ Kb, const bf16_t* __restrict__ Vtb,
    bf16x8* Ks, bf16x8* Vs, bf16_t* Pw,
    const bf16x8 (&qf)[6], f32x4 (&oacc)[8], float (&mrun)[4], float (&lrun)[4],
    int tid, int l15, int l4, int qrow) {
  const f32x4 Z4 = {0.f, 0.f, 0.f, 0.f};
  __syncthreads();
#pragma unroll
  for (int i = 0; i < 6; ++i) {
    int c = tid + i * 256;
    int row = c / 24, kc = c - row * 24;
    Ks[row * 24 + ((kc & ~7) | ((kc ^ row) & 7))] =
        reinterpret_cast<const bf16x8*>(Kb + (bhNS + kv0 + row) * QKD)[kc];
  }
#pragma unroll
  for (int i = 0; i < 4; ++i) {
    int c = tid + i * 256;
    int row = c >> 3, kc = c & 7;
    Vs[row * 8 + (kc ^ (row & 7))] =
        reinterpret_cast<const bf16x8*>(Vtb + (bhDV + row) * NS + kv0)[kc];
  }
  __syncthreads();

  f32x4 sacc[4];
#pragma unroll
  for (int sub = 0; sub < 4; ++sub) {
    sacc[sub] = Z4;
#pragma unroll
    for (int ksc = 0; ksc < 6; ++ksc) {
      int row = sub * 16 + l15;
      int kc = ksc * 4 + l4;
      bf16x8 kf = Ks[row * 24 + ((kc & ~7) | ((kc ^ row) & 7))];
      sacc[sub] = __builtin_amdgcn_mfma_f32_16x16x32_bf16(qf[ksc], kf, sacc[sub], 0, 0, 0);
    }
  }

  float sbuf[4][4];
  float mloc[4] = {-3e38f, -3e38f, -3e38f, -3e38f};
#pragma unroll
  for (int sub = 0; sub < 4; ++sub) {
#pragma unroll
    for (int r = 0; r < 4; ++r) {
      float s = sacc[sub][r];
      if (MASK) {
        int colg = kv0 + sub * 16 + l15;
        int rowg = qrow + l4 * 4 + r;
        if (colg > rowg) s = -3e38f;
      }
      sbuf[sub][r] = s;
      mloc[r] = fmaxf(mloc[r], s);
    }
  }
#pragma unroll
  for (int m = 1; m < 16; m <<= 1)
#pragma unroll
    for (int r = 0; r < 4; ++r) mloc[r] = fmaxf(mloc[r], __shfl_xor(mloc[r], m));

  // exact skip-rescale: if no row's max grew (all 64 lanes), fac==1 -> skip
  float d0 = fmaxf(fmaxf(mloc[0] - mrun[0], mloc[1] - mrun[1]),
                   fmaxf(mloc[2] - mrun[2], mloc[3] - mrun[3]));
  if (!__all(d0 <= 0.f)) {
#pragma unroll
    for (int r = 0; r < 4; ++r) {
      float mn = fmaxf(mrun[r], mloc[r]);
      float fac = EXP2F(mrun[r] - mn);
      mrun[r] = mn;
      lrun[r] *= fac;
#pragma unroll
      for (int dc = 0; dc < 8; ++dc) oacc[dc][r] *= fac;
    }
  }

  float rsum[4] = {0.f, 0.f, 0.f, 0.f};
#pragma unroll
  for (int sub = 0; sub < 4; ++sub) {
#pragma unroll
    for (int r = 0; r < 4; ++r) {
      float p = EXP2F(sbuf[sub][r] - mrun[r]);
      rsum[r] += p;
      int prow = l4 * 4 + r;
      int pcol = sub * 16 + l15;
      Pw[prow * 64 + (((pcol >> 3) ^ (prow & 7)) << 3) + (pcol & 7)] = (bf16_t)p;
    }
  }
#pragma unroll
  for (int m = 1; m < 16; m <<= 1)
#pragma unroll
    for (int r = 0; r < 4; ++r) rsum[r] += __shfl_xor(rsum[r], m);
#pragma unroll
  for (int r = 0; r < 4; ++r) lrun[r] += rsum[r];

#pragma unroll
  for (int ks = 0; ks < 2; ++ks) {
    int kc = ks * 4 + l4;
    bf16x8 paf = reinterpret_cast<bf16x8*>(Pw)[l15 * 8 + (kc ^ (l15 & 7))];
#pragma unroll
    for (int dc = 0; dc < 8; ++dc) {
      int vrow = dc * 16 + l15;
      bf16x8 vf = Vs[vrow * 8 + (kc ^ (vrow & 7))];
      oacc[dc] = __builtin_amdgcn_mfma_f32_16x16x32_bf16(paf, vf, oacc[dc], 0, 0, 0);
    }
  }
}

// ---------------- flash attention (causal), paired q-tiles + XCD swizzle ----------------
__global__ __launch_bounds__(256) void k_attn(const bf16_t* __restrict__ Qb,
                                              const bf16_t* __restrict__ Kb,
                                              const bf16_t* __restrict__ Vtb,
                                              bf16_t* __restrict__ Ao) {
  __shared__ bf16x8 Ks[64 * 24];
  __shared__ bf16x8 Vs[128 * 8];
  __shared__ bf16x8 Ps[4 * 16 * 8];
  // XCD swizzle: all 16 q-pair blocks of one (b,h) land on one XCD for K/V L2 reuse
  const int id = blockIdx.x;
  const int xcd = id & 7, slot = id >> 3;
  const int bh = xcd + 8 * (slot >> 4);
  const int bx = slot & 15;
  const int b = bh >> 4, h = bh & 15;
  const int tid = threadIdx.x;
  const int lane = tid & 63, wave = tid >> 6;
  const int l15 = lane & 15, l4 = lane >> 4;
  const size_t bhNS = (size_t)bh * NS;
  const size_t bhDV = (size_t)bh * DVDIM;
  bf16_t* Pw = reinterpret_cast<bf16_t*>(&Ps[wave * 128]);

#pragma unroll 1
  for (int phase = 0; phase < 2; ++phase) {
    const int qt = (phase == 0) ? (31 - bx) : bx;
    const int q0 = qt * 64;
    const int qrow = q0 + wave * 16;

    bf16x8 qf[6];
    {
      const bf16_t* qrp = Qb + (bhNS + qrow + l15) * QKD;
#pragma unroll
      for (int kc = 0; kc < 6; ++kc)
        qf[kc] = reinterpret_cast<const bf16x8*>(qrp)[kc * 4 + l4];
    }

    const f32x4 Z4 = {0.f, 0.f, 0.f, 0.f};
    f32x4 oacc[8];
#pragma unroll
    for (int i = 0; i < 8; ++i) oacc[i] = Z4;
    float mrun[4], lrun[4];
#pragma unroll
    for (int r = 0; r < 4; ++r) {
      mrun[r] = -3e38f;
      lrun[r] = 0.f;
    }

    for (int kt = 0; kt < qt; ++kt)
      attn_tile<false>(kt * 64, bhNS, bhDV, Kb, Vtb, Ks, Vs, Pw, qf, oacc, mrun, lrun,
                       tid, l15, l4, qrow);
    attn_tile<true>(q0, bhNS, bhDV, Kb, Vtb, Ks, Vs, Pw, qf, oacc, mrun, lrun,
                    tid, l15, l4, qrow);

#pragma unroll
    for (int r = 0; r < 4; ++r) lrun[r] = RCPF(lrun[r]);
#pragma unroll
    for (int dc = 0; dc < 8; ++dc) {
      int dv = dc * 16 + l15;
#pragma unroll
      for (int r = 0; r < 4; ++r) {
        int rowg = q0 + wave * 16 + l4 * 4 + r;
        float v = oacc[dc][r] * lrun[r];
        Ao[((size_t)(b * NS + rowg)) * (NH * DVDIM) + h * DVDIM + dv] = (bf16_t)v;
      }
    }
  }
}

// ---------------- launch ----------------
extern "C" void kernel_launch(void* const* d_in, const int* in_sizes, int n_in,
                              void* d_out, int out_size, void* d_ws, size_t ws_size,
                              hipStream_t stream) {
  (void)in_sizes; (void)n_in; (void)out_size; (void)ws_size;
  const float* x = (const float*)d_in[0];
  const float* fcos = (const float*)d_in[1];
  const float* fsin = (const float*)d_in[2];
  const float* wq_a = (const float*)d_in[4];
  const float* q_norm_w = (const float*)d_in[5];
  const float* wq_b = (const float*)d_in[6];
  const float* wkv_a = (const float*)d_in[7];
  const float* kv_norm_w = (const float*)d_in[8];
  const float* wkv_b = (const float*)d_in[9];
  const float* wo = (const float*)d_in[10];
  float* out = (float*)d_out;

  char* p = (char*)d_ws;
  bf16_t* x_bf = (bf16_t*)(p);
  bf16_t* wqa_bf = (bf16_t*)(p + 16777216);
  bf16_t* wqb_bf = (bf16_t*)(p + 23068672);
  bf16_t* wkva_bf = (bf16_t*)(p + 32505856);
  bf16_t* wkvb_bf = (bf16_t*)(p + 34865152);
  bf16_t* wo_bf = (bf16_t*)(p + 39059456);
  float* qa_f32 = (float*)(p + 47448064);
  bf16_t* Kb = (bf16_t*)(p + 47448064);
  bf16_t* qan_bf = (bf16_t*)(p + 72613888);
  bf16_t* Qb = (bf16_t*)(p + 85196800);
  char* r2 = p + 110362624;
  float* q_f32 = (float*)(r2);
  float* kvf_f32 = (float*)(r2);
  bf16_t* kvn_bf = (bf16_t*)(r2 + 9437184);
  bf16_t* Vtb = (bf16_t*)(r2 + 13631488);
  bf16_t* attn_bf = (bf16_t*)(r2 + 30408704);

  auto cvt = [&](const float* src, bf16_t* dst, size_t n) {
    int n4 = (int)(n / 4);
    int grid = (n4 + 255) / 256;
    k_cvt<<<grid, 256, 0, stream>>>(src, dst, n4);
  };
  cvt(x, x_bf, (size_t)NB * NS * ND);
  cvt(wq_a, wqa_bf, (size_t)QLORA * ND);
  cvt(wq_b, wqb_bf, (size_t)(NH * QKD) * QLORA);
  cvt(wkv_a, wkva_bf, (size_t)(KVLORA + DROPE) * ND);
  cvt(wkv_b, wkvb_bf, (size_t)(NH * (DNOPE + DVDIM)) * KVLORA);
  cvt(wo, wo_bf, (size_t)ND * (NH * DVDIM));

  k_gemm_bt<0><<<dim3(12, 32), 256, 0, stream>>>(x_bf, wqa_bf, qa_f32, nullptr, nullptr,
                                                 NB * NS, QLORA, ND);
  k_rmsnorm<QLORA><<<NB * NS, 256, 0, stream>>>(qa_f32, q_norm_w, qan_bf);
  k_gemm_bt<0><<<dim3(24, 32), 256, 0, stream>>>(qan_bf, wqb_bf, q_f32, nullptr, nullptr,
                                                 NB * NS, NH * QKD, QLORA);
  {
    int total = NB * NS * NH * (QKD / 2);
    k_rope_q<<<(total + 255) / 256, 256, 0, stream>>>(q_f32, fcos, fsin, Qb);
  }
  k_gemm_bt<0><<<dim3(5, 32), 256, 0, stream>>>(x_bf, wkva_bf, kvf_f32, nullptr, nullptr,
                                                NB * NS, KVLORA + DROPE, ND);
  k_kv_post<<<NB * NS, 256, 0, stream>>>(kvf_f32, kv_norm_w, fcos, fsin, kvn_bf, Kb);
  k_gemm_bt<1><<<dim3(32, 32), 256, 0, stream>>>(kvn_bf, wkvb_bf, nullptr, Kb, Vtb,
                                                 NB * NS, NH * (DNOPE + DVDIM), KVLORA);
  k_attn<<<dim3(512), 256, 0, stream>>>(Qb, Kb, Vtb, attn_bf);
  k_gemm_bt<0><<<dim3(16, 32), 256, 0, stream>>>(attn_bf, wo_bf, out, nullptr, nullptr,
                                                 NB * NS, ND, NH * DVDIM);
}

// Round 5
// 412.919 us; speedup vs baseline: 1.4307x; 1.0469x over previous
//
#include <hip/hip_runtime.h>
#include <hip/hip_bf16.h>

typedef __bf16 bf16_t;
typedef __bf16 bf16x8 __attribute__((ext_vector_type(8)));
typedef __bf16 bf16x4 __attribute__((ext_vector_type(4)));
typedef float  f32x4  __attribute__((ext_vector_type(4)));

#define NB 2
#define NS 2048
#define ND 2048
#define NH 16
#define QLORA 1536
#define KVLORA 512
#define DNOPE 128
#define DROPE 64
#define DVDIM 128
#define QKD 192

// 1/sqrt(192) * log2(e): Q is pre-scaled by this so QK^T lands in exp2 domain.
#define QSCALE 0.10411754f

#if __has_builtin(__builtin_amdgcn_exp2f)
#define EXP2F(x) __builtin_amdgcn_exp2f(x)
#else
#define EXP2F(x) __expf((x) * 0.69314718056f)
#endif
#if __has_builtin(__builtin_amdgcn_rcpf)
#define RCPF(x) __builtin_amdgcn_rcpf(x)
#else
#define RCPF(x) (1.0f / (x))
#endif

typedef __attribute__((address_space(3))) void as3_void;
typedef __attribute__((address_space(1))) const void as1_void;
__device__ __forceinline__ void gload16(const void* g, void* l) {
  __builtin_amdgcn_global_load_lds((as1_void*)g, (as3_void*)l, 16, 0, 0);
}

// ---------------- fused f32 -> bf16 convert for all 6 tensors ----------------
__global__ __launch_bounds__(256) void k_cvt_all(
    const float* __restrict__ x, const float* __restrict__ wqa,
    const float* __restrict__ wqb, const float* __restrict__ wkva,
    const float* __restrict__ wkvb, const float* __restrict__ wo,
    bf16_t* __restrict__ xb, bf16_t* __restrict__ wqab, bf16_t* __restrict__ wqbb,
    bf16_t* __restrict__ wkvab, bf16_t* __restrict__ wkvbb, bf16_t* __restrict__ wob) {
  // segment boundaries in float4 units
  const int c0 = 2097152, c1 = 2883584, c2 = 4063232, c3 = 4358144, c4 = 4882432,
            c5 = 5931008;
  int i = blockIdx.x * 256 + threadIdx.x;
  for (; i < c5; i += gridDim.x * 256) {
    const float* src;
    bf16_t* dst;
    int off;
    if (i < c0) { src = x; dst = xb; off = i; }
    else if (i < c1) { src = wqa; dst = wqab; off = i - c0; }
    else if (i < c2) { src = wqb; dst = wqbb; off = i - c1; }
    else if (i < c3) { src = wkva; dst = wkvab; off = i - c2; }
    else if (i < c4) { src = wkvb; dst = wkvbb; off = i - c3; }
    else { src = wo; dst = wob; off = i - c4; }
    float4 v = reinterpret_cast<const float4*>(src)[off];
    bf16x4 o = {(bf16_t)v.x, (bf16_t)v.y, (bf16_t)v.z, (bf16_t)v.w};
    reinterpret_cast<bf16x4*>(dst)[off] = o;
  }
}

// ---------------- generic bf16 GEMM: C[M,N] = A[M,K] * Bw[N,K]^T ----------------
// EPI 0: f32 store; EPI 1: kv scatter (K-nope + V^T); EPI 2: fused RoPE -> Qb bf16
template <int EPI>
__global__ __launch_bounds__(256) void k_gemm_bt(
    const bf16_t* __restrict__ A, const bf16_t* __restrict__ Bw,
    float* __restrict__ Cf, bf16_t* __restrict__ Kout, bf16_t* __restrict__ Vtout,
    const float* __restrict__ fc, const float* __restrict__ fs,
    int M, int N, int K) {
  __shared__ bf16_t As[128 * 64];
  __shared__ bf16_t Bs[128 * 64];
  const int tid = threadIdx.x;
  const int lane = tid & 63;
  const int wave = tid >> 6;
  const int wm = (wave >> 1) * 64, wn = (wave & 1) * 64;
  const int m0 = blockIdx.y * 128, n0 = blockIdx.x * 128;
  const int l15 = lane & 15, l4 = lane >> 4;
  const int srow = lane >> 3;
  const int scol = (lane & 7) * 8;

  const f32x4 Z4 = {0.f, 0.f, 0.f, 0.f};
  f32x4 acc[4][4];
#pragma unroll
  for (int i = 0; i < 4; ++i)
#pragma unroll
    for (int j = 0; j < 4; ++j) acc[i][j] = Z4;

  for (int k0 = 0; k0 < K; k0 += 64) {
    __syncthreads();
#pragma unroll
    for (int c = 0; c < 4; ++c) {
      int chunk = c * 4 + wave;
      int row = chunk * 8 + srow;
      gload16(A + (size_t)(m0 + row) * K + k0 + scol, &As[chunk * 512]);
      gload16(Bw + (size_t)(n0 + row) * K + k0 + scol, &Bs[chunk * 512]);
    }
    __syncthreads();
#pragma unroll
    for (int ks = 0; ks < 2; ++ks) {
      int kc = ks * 4 + l4;
      bf16x8 af[4], bfr[4];
#pragma unroll
      for (int f = 0; f < 4; ++f) {
        af[f] = *reinterpret_cast<const bf16x8*>(&As[(wm + f * 16 + l15) * 64 + kc * 8]);
        bfr[f] = *reinterpret_cast<const bf16x8*>(&Bs[(wn + f * 16 + l15) * 64 + kc * 8]);
      }
#pragma unroll
      for (int fi = 0; fi < 4; ++fi)
#pragma unroll
        for (int fj = 0; fj < 4; ++fj)
          acc[fi][fj] = __builtin_amdgcn_mfma_f32_16x16x32_bf16(af[fi], bfr[fj], acc[fi][fj], 0, 0, 0);
    }
  }

#pragma unroll
  for (int fi = 0; fi < 4; ++fi) {
#pragma unroll
    for (int fj = 0; fj < 4; ++fj) {
      int col = n0 + wn + fj * 16 + l15;
#pragma unroll
      for (int r = 0; r < 4; ++r) {
        int row = m0 + wm + fi * 16 + l4 * 4 + r;
        float v = acc[fi][fj][r];
        if (EPI == 0) {
          if (col < N) Cf[(size_t)row * N + col] = v;
        } else if (EPI == 1) {
          int h = col >> 8, rr = col & 255;
          int b = row >> 11, s = row & 2047;
          if (rr < DNOPE)
            Kout[(((size_t)(b * NH + h)) * NS + s) * QKD + rr] = (bf16_t)v;
          else
            Vtout[(((size_t)(b * NH + h)) * DVDIM + (rr - DNOPE)) * NS + s] = (bf16_t)v;
        } else {
          // EPI 2: q RoPE fused. col = h*192 + d (16-col groups never straddle
          // the 128 boundary or a head boundary: both are multiples of 16).
          int h = col / 192;
          int d = col - h * 192;
          int b = row >> 11, s = row & 2047;
          float y = v;
          if (d >= DNOPE) {
            float pv = __shfl_xor(v, 1);  // partner col = col^1
            int pp = ((d & ~1) - DNOPE) >> 1;
            float c = fc[s * 32 + pp], si = fs[s * 32 + pp];
            y = (col & 1) ? (pv * si + v * c) : (v * c - pv * si);
          }
          Kout[((size_t)(b * NH + h) * NS + s) * QKD + d] = (bf16_t)(y * QSCALE);
        }
      }
    }
  }
}

// ---------------- RMS norm over rows (f32 in, bf16 out) ----------------
template <int COLS>
__global__ __launch_bounds__(256) void k_rmsnorm(const float* __restrict__ in,
                                                 const float* __restrict__ w,
                                                 bf16_t* __restrict__ out) {
  int row = blockIdx.x;
  const float* rp = in + (size_t)row * COLS;
  float ss = 0.f;
  for (int c = threadIdx.x * 4; c < COLS; c += 1024) {
    float4 v = *reinterpret_cast<const float4*>(rp + c);
    ss += v.x * v.x + v.y * v.y + v.z * v.z + v.w * v.w;
  }
#pragma unroll
  for (int m = 32; m; m >>= 1) ss += __shfl_xor(ss, m);
  __shared__ float red[4];
  if ((threadIdx.x & 63) == 0) red[threadIdx.x >> 6] = ss;
  __syncthreads();
  float tot = red[0] + red[1] + red[2] + red[3];
  float rs = rsqrtf(tot / (float)COLS + 1e-6f);
  for (int c = threadIdx.x * 4; c < COLS; c += 1024) {
    float4 v = *reinterpret_cast<const float4*>(rp + c);
    bf16x4 o = {(bf16_t)(v.x * rs * w[c]), (bf16_t)(v.y * rs * w[c + 1]),
                (bf16_t)(v.z * rs * w[c + 2]), (bf16_t)(v.w * rs * w[c + 3])};
    *reinterpret_cast<bf16x4*>(out + (size_t)row * COLS + c) = o;
  }
}

// ---------------- kv post: RMS norm 512 -> bf16, RoPE k_pe -> broadcast to K ----------------
__global__ __launch_bounds__(256) void k_kv_post(const float* __restrict__ kvf,
                                                 const float* __restrict__ w,
                                                 const float* __restrict__ fc,
                                                 const float* __restrict__ fs,
                                                 bf16_t* __restrict__ kvn,
                                                 bf16_t* __restrict__ Kb) {
  int row = blockIdx.x;  // token
  const float* rp = kvf + (size_t)row * (KVLORA + DROPE);
  float ss = 0.f;
  float4 v = {0.f, 0.f, 0.f, 0.f};
  if (threadIdx.x < 128) {
    v = reinterpret_cast<const float4*>(rp)[threadIdx.x];
    ss = v.x * v.x + v.y * v.y + v.z * v.z + v.w * v.w;
  }
#pragma unroll
  for (int m = 32; m; m >>= 1) ss += __shfl_xor(ss, m);
  __shared__ float red[4];
  if ((threadIdx.x & 63) == 0) red[threadIdx.x >> 6] = ss;
  __syncthreads();
  float tot = red[0] + red[1] + red[2] + red[3];
  float rs = rsqrtf(tot / (float)KVLORA + 1e-6f);
  if (threadIdx.x < 128) {
    int c = threadIdx.x * 4;
    bf16x4 o = {(bf16_t)(v.x * rs * w[c]), (bf16_t)(v.y * rs * w[c + 1]),
                (bf16_t)(v.z * rs * w[c + 2]), (bf16_t)(v.w * rs * w[c + 3])};
    *reinterpret_cast<bf16x4*>(kvn + (size_t)row * KVLORA + c) = o;
  }
  int b = row >> 11, s = row & 2047;
  if (threadIdx.x < 32) {
    int p = threadIdx.x;
    float x0 = rp[KVLORA + 2 * p], x1 = rp[KVLORA + 2 * p + 1];
    float c = fc[s * 32 + p], si = fs[s * 32 + p];
    float yr = x0 * c - x1 * si, yi = x0 * si + x1 * c;
    bf16_t br = (bf16_t)yr, bi = (bf16_t)yi;
    for (int h = 0; h < NH; ++h) {
      size_t ob = ((size_t)(b * NH + h) * NS + s) * QKD + DNOPE;
      Kb[ob + 2 * p] = br;
      Kb[ob + 2 * p + 1] = bi;
    }
  }
}

// ---------------- flash attention: QBLK=128, 8 waves, async reg prefetch ----------------
__global__ __launch_bounds__(512) void k_attn(const bf16_t* __restrict__ Qb,
                                              const bf16_t* __restrict__ Kb,
                                              const bf16_t* __restrict__ Vtb,
                                              bf16_t* __restrict__ Ao) {
  __shared__ bf16x8 Ks[64 * 24];
  __shared__ bf16x8 Vs[128 * 8];
  __shared__ bf16x8 Ps[8 * 16 * 8];
  // XCD swizzle: 8 blocks of one (b,h) land on one XCD for K/V L2 reuse
  const int id = blockIdx.x;
  const int s_ = id >> 3;
  const int bh = (id & 7) + 8 * (s_ & 3);
  const int bx = s_ >> 2;  // 0..7 pair index
  const int b = bh >> 4, h = bh & 15;
  const int tid = threadIdx.x;
  const int lane = tid & 63, wave = tid >> 6;
  const int l15 = lane & 15, l4 = lane >> 4;
  const size_t bhNS = (size_t)bh * NS;
  const size_t bhDV = (size_t)bh * DVDIM;
  bf16_t* Pw = reinterpret_cast<bf16_t*>(&Ps[wave * 128]);
  const f32x4 Z4 = {0.f, 0.f, 0.f, 0.f};

  // staging decomposition (512 threads): K 1536 chunks x3, V 1024 chunks x2
  int krow[3], kkc[3], vrw[2], vkc[2];
#pragma unroll
  for (int i = 0; i < 3; ++i) {
    int c = tid + i * 512;
    krow[i] = c / 24;
    kkc[i] = c - krow[i] * 24;
  }
#pragma unroll
  for (int i = 0; i < 2; ++i) {
    int c = tid + i * 512;
    vrw[i] = c >> 3;
    vkc[i] = c & 7;
  }

#pragma unroll 1
  for (int phase = 0; phase < 2; ++phase) {
    const int qt = (phase == 0) ? (15 - bx) : bx;
    const int q0 = qt * 128;
    const int qrow = q0 + wave * 16;
    const int ntiles = 2 * qt + 2;

    bf16x8 qf[6];
    {
      const bf16_t* qrp = Qb + (bhNS + qrow + l15) * QKD;
#pragma unroll
      for (int kc = 0; kc < 6; ++kc)
        qf[kc] = reinterpret_cast<const bf16x8*>(qrp)[kc * 4 + l4];
    }

    f32x4 oacc[8];
#pragma unroll
    for (int i = 0; i < 8; ++i) oacc[i] = Z4;
    float mrun[4], lrun[4];
#pragma unroll
    for (int r = 0; r < 4; ++r) {
      mrun[r] = -3e38f;
      lrun[r] = 0.f;
    }

    // prefetch tile 0 into registers
    bf16x8 kpre[3], vpre[2];
#pragma unroll
    for (int i = 0; i < 3; ++i)
      kpre[i] = reinterpret_cast<const bf16x8*>(Kb + (bhNS + krow[i]) * QKD)[kkc[i]];
#pragma unroll
    for (int i = 0; i < 2; ++i)
      vpre[i] = reinterpret_cast<const bf16x8*>(Vtb + (bhDV + vrw[i]) * NS)[vkc[i]];

#pragma unroll 1
    for (int kt = 0; kt < ntiles; ++kt) {
      const int kv0 = kt * 64;
      __builtin_amdgcn_sched_barrier(0);
      __builtin_amdgcn_s_barrier();  // prev compute done reading LDS
      // commit prefetched tile to LDS (compiler inserts vmcnt waits)
#pragma unroll
      for (int i = 0; i < 3; ++i)
        Ks[krow[i] * 24 + ((kkc[i] & ~7) | ((kkc[i] ^ krow[i]) & 7))] = kpre[i];
#pragma unroll
      for (int i = 0; i < 2; ++i)
        Vs[vrw[i] * 8 + (vkc[i] ^ (vrw[i] & 7))] = vpre[i];
      // issue prefetch of next tile (overlaps with compute below)
      if (kt + 1 < ntiles) {
        const int nk = kv0 + 64;
#pragma unroll
        for (int i = 0; i < 3; ++i)
          kpre[i] = reinterpret_cast<const bf16x8*>(Kb + (bhNS + nk + krow[i]) * QKD)[kkc[i]];
#pragma unroll
        for (int i = 0; i < 2; ++i)
          vpre[i] = reinterpret_cast<const bf16x8*>(Vtb + (bhDV + vrw[i]) * NS + nk)[vkc[i]];
      }
      __builtin_amdgcn_sched_barrier(0);
      asm volatile("s_waitcnt lgkmcnt(0)" ::: "memory");
      __builtin_amdgcn_s_barrier();  // LDS ready
      __builtin_amdgcn_sched_barrier(0);

      if (qrow + 15 >= kv0) {  // wave has at least one unmasked row
        f32x4 sacc[4];
#pragma unroll
        for (int sub = 0; sub < 4; ++sub) {
          sacc[sub] = Z4;
#pragma unroll
          for (int ksc = 0; ksc < 6; ++ksc) {
            int row = sub * 16 + l15;
            int kc = ksc * 4 + l4;
            bf16x8 kf = Ks[row * 24 + ((kc & ~7) | ((kc ^ row) & 7))];
            sacc[sub] = __builtin_amdgcn_mfma_f32_16x16x32_bf16(qf[ksc], kf, sacc[sub], 0, 0, 0);
          }
        }

        float sbuf[4][4];
        float mloc[4] = {-3e38f, -3e38f, -3e38f, -3e38f};
        const bool msk = (kv0 >= q0);
#pragma unroll
        for (int sub = 0; sub < 4; ++sub) {
#pragma unroll
          for (int r = 0; r < 4; ++r) {
            float s = sacc[sub][r];
            if (msk) {
              int colg = kv0 + sub * 16 + l15;
              int rowg = qrow + l4 * 4 + r;
              if (colg > rowg) s = -3e38f;
            }
            sbuf[sub][r] = s;
            mloc[r] = fmaxf(mloc[r], s);
          }
        }
#pragma unroll
        for (int m = 1; m < 16; m <<= 1)
#pragma unroll
          for (int r = 0; r < 4; ++r) mloc[r] = fmaxf(mloc[r], __shfl_xor(mloc[r], m));

        float d0 = fmaxf(fmaxf(mloc[0] - mrun[0], mloc[1] - mrun[1]),
                         fmaxf(mloc[2] - mrun[2], mloc[3] - mrun[3]));
        if (!__all(d0 <= 0.f)) {
#pragma unroll
          for (int r = 0; r < 4; ++r) {
            float mn = fmaxf(mrun[r], mloc[r]);
            float fac = EXP2F(mrun[r] - mn);
            mrun[r] = mn;
            lrun[r] *= fac;
#pragma unroll
            for (int dc = 0; dc < 8; ++dc) oacc[dc][r] *= fac;
          }
        }

        float rsum[4] = {0.f, 0.f, 0.f, 0.f};
#pragma unroll
        for (int sub = 0; sub < 4; ++sub) {
#pragma unroll
          for (int r = 0; r < 4; ++r) {
            float p = EXP2F(sbuf[sub][r] - mrun[r]);
            rsum[r] += p;
            int prow = l4 * 4 + r;
            int pcol = sub * 16 + l15;
            Pw[prow * 64 + (((pcol >> 3) ^ (prow & 7)) << 3) + (pcol & 7)] = (bf16_t)p;
          }
        }
#pragma unroll
        for (int m = 1; m < 16; m <<= 1)
#pragma unroll
          for (int r = 0; r < 4; ++r) rsum[r] += __shfl_xor(rsum[r], m);
#pragma unroll
        for (int r = 0; r < 4; ++r) lrun[r] += rsum[r];

#pragma unroll
        for (int ks = 0; ks < 2; ++ks) {
          int kc = ks * 4 + l4;
          bf16x8 paf = reinterpret_cast<bf16x8*>(Pw)[l15 * 8 + (kc ^ (l15 & 7))];
#pragma unroll
          for (int dc = 0; dc < 8; ++dc) {
            int vrow = dc * 16 + l15;
            bf16x8 vf = Vs[vrow * 8 + (kc ^ (vrow & 7))];
            oacc[dc] = __builtin_amdgcn_mfma_f32_16x16x32_bf16(paf, vf, oacc[dc], 0, 0, 0);
          }
        }
      }
    }

#pragma unroll
    for (int r = 0; r < 4; ++r) lrun[r] = RCPF(lrun[r]);
#pragma unroll
    for (int dc = 0; dc < 8; ++dc) {
      int dv = dc * 16 + l15;
#pragma unroll
      for (int r = 0; r < 4; ++r) {
        int rowg = qrow + l4 * 4 + r;
        float v = oacc[dc][r] * lrun[r];
        Ao[((size_t)(b * NS + rowg)) * (NH * DVDIM) + h * DVDIM + dv] = (bf16_t)v;
      }
    }
  }
}

// ---------------- launch ----------------
extern "C" void kernel_launch(void* const* d_in, const int* in_sizes, int n_in,
                              void* d_out, int out_size, void* d_ws, size_t ws_size,
                              hipStream_t stream) {
  (void)in_sizes; (void)n_in; (void)out_size; (void)ws_size;
  const float* x = (const float*)d_in[0];
  const float* fcos = (const float*)d_in[1];
  const float* fsin = (const float*)d_in[2];
  const float* wq_a = (const float*)d_in[4];
  const float* q_norm_w = (const float*)d_in[5];
  const float* wq_b = (const float*)d_in[6];
  const float* wkv_a = (const float*)d_in[7];
  const float* kv_norm_w = (const float*)d_in[8];
  const float* wkv_b = (const float*)d_in[9];
  const float* wo = (const float*)d_in[10];
  float* out = (float*)d_out;

  char* p = (char*)d_ws;
  bf16_t* x_bf = (bf16_t*)(p);
  bf16_t* wqa_bf = (bf16_t*)(p + 16777216);
  bf16_t* wqb_bf = (bf16_t*)(p + 23068672);
  bf16_t* wkva_bf = (bf16_t*)(p + 32505856);
  bf16_t* wkvb_bf = (bf16_t*)(p + 34865152);
  bf16_t* wo_bf = (bf16_t*)(p + 39059456);
  float* qa_f32 = (float*)(p + 47448064);
  bf16_t* Kb = (bf16_t*)(p + 47448064);  // union with qa_f32 (qa dead after rmsnorm)
  bf16_t* qan_bf = (bf16_t*)(p + 72613888);
  bf16_t* Qb = (bf16_t*)(p + 85196800);
  char* r2 = p + 110362624;
  float* kvf_f32 = (float*)(r2);
  bf16_t* kvn_bf = (bf16_t*)(r2 + 9437184);
  bf16_t* Vtb = (bf16_t*)(r2 + 13631488);
  bf16_t* attn_bf = (bf16_t*)(r2 + 30408704);

  k_cvt_all<<<2048, 256, 0, stream>>>(x, wq_a, wq_b, wkv_a, wkv_b, wo, x_bf, wqa_bf,
                                      wqb_bf, wkva_bf, wkvb_bf, wo_bf);

  // q_a = x @ wq_a^T   [4096,1536] f32
  k_gemm_bt<0><<<dim3(12, 32), 256, 0, stream>>>(x_bf, wqa_bf, qa_f32, nullptr, nullptr,
                                                 nullptr, nullptr, NB * NS, QLORA, ND);
  k_rmsnorm<QLORA><<<NB * NS, 256, 0, stream>>>(qa_f32, q_norm_w, qan_bf);
  // q = q_a_n @ wq_b^T [4096,3072] -> fused RoPE -> Qb [B*H,S,192]
  k_gemm_bt<2><<<dim3(24, 32), 256, 0, stream>>>(qan_bf, wqb_bf, nullptr, Qb, nullptr,
                                                 fcos, fsin, NB * NS, NH * QKD, QLORA);
  // kv_full = x @ wkv_a^T [4096,576] f32
  k_gemm_bt<0><<<dim3(5, 32), 256, 0, stream>>>(x_bf, wkva_bf, kvf_f32, nullptr, nullptr,
                                                nullptr, nullptr, NB * NS, KVLORA + DROPE, ND);
  k_kv_post<<<NB * NS, 256, 0, stream>>>(kvf_f32, kv_norm_w, fcos, fsin, kvn_bf, Kb);
  // kv_b = kv_n @ wkv_b^T [4096,4096] -> scatter K (nope) + V^T
  k_gemm_bt<1><<<dim3(32, 32), 256, 0, stream>>>(kvn_bf, wkvb_bf, nullptr, Kb, Vtb,
                                                 nullptr, nullptr, NB * NS,
                                                 NH * (DNOPE + DVDIM), KVLORA);
  // attention: QBLK=128, supertile pairs, grid 256 x 512 threads
  k_attn<<<dim3(256), 512, 0, stream>>>(Qb, Kb, Vtb, attn_bf);
  // out = attn @ wo^T  [4096,2048] f32
  k_gemm_bt<0><<<dim3(16, 32), 256, 0, stream>>>(attn_bf, wo_bf, out, nullptr, nullptr,
                                                 nullptr, nullptr, NB * NS, ND, NH * DVDIM);
}

// Round 6
// 367.425 us; speedup vs baseline: 1.6079x; 1.1238x over previous
//
#include <hip/hip_runtime.h>
#include <hip/hip_bf16.h>

typedef __bf16 bf16_t;
typedef __bf16 bf16x8 __attribute__((ext_vector_type(8)));
typedef __bf16 bf16x4 __attribute__((ext_vector_type(4)));
typedef float  f32x4  __attribute__((ext_vector_type(4)));

#define NB 2
#define NS 2048
#define ND 2048
#define NH 16
#define QLORA 1536
#define KVLORA 512
#define DNOPE 128
#define DROPE 64
#define DVDIM 128
#define QKD 192

// 1/sqrt(192) * log2(e): Q is pre-scaled by this so QK^T lands in exp2 domain.
#define QSCALE 0.10411754f

#if __has_builtin(__builtin_amdgcn_exp2f)
#define EXP2F(x) __builtin_amdgcn_exp2f(x)
#else
#define EXP2F(x) __expf((x) * 0.69314718056f)
#endif
#if __has_builtin(__builtin_amdgcn_rcpf)
#define RCPF(x) __builtin_amdgcn_rcpf(x)
#else
#define RCPF(x) (1.0f / (x))
#endif

typedef __attribute__((address_space(3))) void as3_void;
typedef __attribute__((address_space(1))) const void as1_void;
__device__ __forceinline__ void gload16(const void* g, void* l) {
  __builtin_amdgcn_global_load_lds((as1_void*)g, (as3_void*)l, 16, 0, 0);
}

// ---------------- fused f32 -> bf16 convert for all 6 tensors ----------------
__global__ __launch_bounds__(256) void k_cvt_all(
    const float* __restrict__ x, const float* __restrict__ wqa,
    const float* __restrict__ wqb, const float* __restrict__ wkva,
    const float* __restrict__ wkvb, const float* __restrict__ wo,
    bf16_t* __restrict__ xb, bf16_t* __restrict__ wqab, bf16_t* __restrict__ wqbb,
    bf16_t* __restrict__ wkvab, bf16_t* __restrict__ wkvbb, bf16_t* __restrict__ wob) {
  // segment boundaries in float4 units
  const int c0 = 2097152, c1 = 2883584, c2 = 4063232, c3 = 4358144, c4 = 4882432,
            c5 = 5931008;
  int i = blockIdx.x * 256 + threadIdx.x;
  for (; i < c5; i += gridDim.x * 256) {
    const float* src;
    bf16_t* dst;
    int off;
    if (i < c0) { src = x; dst = xb; off = i; }
    else if (i < c1) { src = wqa; dst = wqab; off = i - c0; }
    else if (i < c2) { src = wqb; dst = wqbb; off = i - c1; }
    else if (i < c3) { src = wkva; dst = wkvab; off = i - c2; }
    else if (i < c4) { src = wkvb; dst = wkvbb; off = i - c3; }
    else { src = wo; dst = wob; off = i - c4; }
    float4 v = reinterpret_cast<const float4*>(src)[off];
    bf16x4 o = {(bf16_t)v.x, (bf16_t)v.y, (bf16_t)v.z, (bf16_t)v.w};
    reinterpret_cast<bf16x4*>(dst)[off] = o;
  }
}

// ---------------- generic bf16 GEMM: C[M,N] = A[M,K] * Bw[N,K]^T ----------------
// Pipelined 2-phase dbuf: stage(t+1) issued before compute(t); one barrier/K-step.
// LDS: linear dest for global_load_lds, source pre-swizzled chunk ((lane&7)^srow),
// reads at phys chunk kc^(row&7) -> 2-way conflicts only (rule 21 both-sides).
// EPI 0: f32 store; EPI 1: kv scatter (K-nope + V^T); EPI 2: fused RoPE -> Qb;
// EPI 3: dual f32 out (col<1536 -> Cf ldc 1536, else Cf2 ldc 576), for q_a+kv_a.
template <int EPI>
__global__ __launch_bounds__(256) void k_gemm_bt(
    const bf16_t* __restrict__ A, const bf16_t* __restrict__ Bw,
    float* __restrict__ Cf, float* __restrict__ Cf2,
    bf16_t* __restrict__ Kout, bf16_t* __restrict__ Vtout,
    const float* __restrict__ fc, const float* __restrict__ fs,
    int M, int N, int K) {
  __shared__ bf16_t As[2][128 * 64];
  __shared__ bf16_t Bs[2][128 * 64];
  const int tid = threadIdx.x;
  const int lane = tid & 63;
  const int wave = tid >> 6;
  const int wm = (wave >> 1) * 64, wn = (wave & 1) * 64;
  const int m0 = blockIdx.y * 128, n0 = blockIdx.x * 128;
  const int l15 = lane & 15, l4 = lane >> 4;
  const int srow = lane >> 3;                  // 0..7 row within chunk
  const int scol = ((lane & 7) ^ srow) * 8;    // pre-swizzled source col chunk

  const f32x4 Z4 = {0.f, 0.f, 0.f, 0.f};
  f32x4 acc[4][4];
#pragma unroll
  for (int i = 0; i < 4; ++i)
#pragma unroll
    for (int j = 0; j < 4; ++j) acc[i][j] = Z4;

  auto stage = [&](int buf, int k0) {
#pragma unroll
    for (int c = 0; c < 4; ++c) {
      int chunk = c * 4 + wave;       // wave-uniform
      int row = chunk * 8 + srow;
      gload16(A + (size_t)(m0 + row) * K + k0 + scol, &As[buf][chunk * 512]);
      gload16(Bw + (size_t)(n0 + row) * K + k0 + scol, &Bs[buf][chunk * 512]);
    }
  };

  const int nk = K >> 6;
  stage(0, 0);
  __syncthreads();
  int cur = 0;
#pragma unroll 1
  for (int t = 0; t < nk; ++t) {
    if (t + 1 < nk) stage(cur ^ 1, (t + 1) * 64);
#pragma unroll
    for (int ks = 0; ks < 2; ++ks) {
      int kc = ks * 4 + l4;
      int pc = (kc ^ (l15 & 7)) * 8;  // phys chunk byte-col (row&7 == l15&7)
      bf16x8 af[4], bfr[4];
#pragma unroll
      for (int f = 0; f < 4; ++f) {
        af[f] = *reinterpret_cast<const bf16x8*>(&As[cur][(wm + f * 16 + l15) * 64 + pc]);
        bfr[f] = *reinterpret_cast<const bf16x8*>(&Bs[cur][(wn + f * 16 + l15) * 64 + pc]);
      }
#pragma unroll
      for (int fi = 0; fi < 4; ++fi)
#pragma unroll
        for (int fj = 0; fj < 4; ++fj)
          acc[fi][fj] = __builtin_amdgcn_mfma_f32_16x16x32_bf16(af[fi], bfr[fj], acc[fi][fj], 0, 0, 0);
    }
    __syncthreads();
    cur ^= 1;
  }

#pragma unroll
  for (int fi = 0; fi < 4; ++fi) {
#pragma unroll
    for (int fj = 0; fj < 4; ++fj) {
      int col = n0 + wn + fj * 16 + l15;
#pragma unroll
      for (int r = 0; r < 4; ++r) {
        int row = m0 + wm + fi * 16 + l4 * 4 + r;
        float v = acc[fi][fj][r];
        if (EPI == 0) {
          if (col < N) Cf[(size_t)row * N + col] = v;
        } else if (EPI == 1) {
          int h = col >> 8, rr = col & 255;
          int b = row >> 11, s = row & 2047;
          if (rr < DNOPE)
            Kout[(((size_t)(b * NH + h)) * NS + s) * QKD + rr] = (bf16_t)v;
          else
            Vtout[(((size_t)(b * NH + h)) * DVDIM + (rr - DNOPE)) * NS + s] = (bf16_t)v;
        } else if (EPI == 2) {
          // fused q RoPE. 16-col groups never straddle head or nope/rope bounds.
          int h = col / 192;
          int d = col - h * 192;
          int b = row >> 11, s = row & 2047;
          float y = v;
          if (d >= DNOPE) {
            float pv = __shfl_xor(v, 1);  // partner col = col^1
            int pp = ((d & ~1) - DNOPE) >> 1;
            float c = fc[s * 32 + pp], si = fs[s * 32 + pp];
            y = (col & 1) ? (pv * si + v * c) : (v * c - pv * si);
          }
          Kout[((size_t)(b * NH + h) * NS + s) * QKD + d] = (bf16_t)(y * QSCALE);
        } else {
          if (col < QLORA) Cf[(size_t)row * QLORA + col] = v;
          else if (col < QLORA + KVLORA + DROPE)
            Cf2[(size_t)row * (KVLORA + DROPE) + (col - QLORA)] = v;
        }
      }
    }
  }
}

// ---------------- RMS norm over rows (f32 in, bf16 out) ----------------
template <int COLS>
__global__ __launch_bounds__(256) void k_rmsnorm(const float* __restrict__ in,
                                                 const float* __restrict__ w,
                                                 bf16_t* __restrict__ out) {
  int row = blockIdx.x;
  const float* rp = in + (size_t)row * COLS;
  float ss = 0.f;
  for (int c = threadIdx.x * 4; c < COLS; c += 1024) {
    float4 v = *reinterpret_cast<const float4*>(rp + c);
    ss += v.x * v.x + v.y * v.y + v.z * v.z + v.w * v.w;
  }
#pragma unroll
  for (int m = 32; m; m >>= 1) ss += __shfl_xor(ss, m);
  __shared__ float red[4];
  if ((threadIdx.x & 63) == 0) red[threadIdx.x >> 6] = ss;
  __syncthreads();
  float tot = red[0] + red[1] + red[2] + red[3];
  float rs = rsqrtf(tot / (float)COLS + 1e-6f);
  for (int c = threadIdx.x * 4; c < COLS; c += 1024) {
    float4 v = *reinterpret_cast<const float4*>(rp + c);
    bf16x4 o = {(bf16_t)(v.x * rs * w[c]), (bf16_t)(v.y * rs * w[c + 1]),
                (bf16_t)(v.z * rs * w[c + 2]), (bf16_t)(v.w * rs * w[c + 3])};
    *reinterpret_cast<bf16x4*>(out + (size_t)row * COLS + c) = o;
  }
}

// ---------------- kv post: RMS norm 512 -> bf16, RoPE k_pe -> broadcast to K ----------------
__global__ __launch_bounds__(256) void k_kv_post(const float* __restrict__ kvf,
                                                 const float* __restrict__ w,
                                                 const float* __restrict__ fc,
                                                 const float* __restrict__ fs,
                                                 bf16_t* __restrict__ kvn,
                                                 bf16_t* __restrict__ Kb) {
  int row = blockIdx.x;  // token
  const float* rp = kvf + (size_t)row * (KVLORA + DROPE);
  float ss = 0.f;
  float4 v = {0.f, 0.f, 0.f, 0.f};
  if (threadIdx.x < 128) {
    v = reinterpret_cast<const float4*>(rp)[threadIdx.x];
    ss = v.x * v.x + v.y * v.y + v.z * v.z + v.w * v.w;
  }
#pragma unroll
  for (int m = 32; m; m >>= 1) ss += __shfl_xor(ss, m);
  __shared__ float red[4];
  if ((threadIdx.x & 63) == 0) red[threadIdx.x >> 6] = ss;
  __syncthreads();
  float tot = red[0] + red[1] + red[2] + red[3];
  float rs = rsqrtf(tot / (float)KVLORA + 1e-6f);
  if (threadIdx.x < 128) {
    int c = threadIdx.x * 4;
    bf16x4 o = {(bf16_t)(v.x * rs * w[c]), (bf16_t)(v.y * rs * w[c + 1]),
                (bf16_t)(v.z * rs * w[c + 2]), (bf16_t)(v.w * rs * w[c + 3])};
    *reinterpret_cast<bf16x4*>(kvn + (size_t)row * KVLORA + c) = o;
  }
  int b = row >> 11, s = row & 2047;
  if (threadIdx.x < 32) {
    int p = threadIdx.x;
    float x0 = rp[KVLORA + 2 * p], x1 = rp[KVLORA + 2 * p + 1];
    float c = fc[s * 32 + p], si = fs[s * 32 + p];
    float yr = x0 * c - x1 * si, yi = x0 * si + x1 * c;
    bf16_t br = (bf16_t)yr, bi = (bf16_t)yi;
    for (int h = 0; h < NH; ++h) {
      size_t ob = ((size_t)(b * NH + h) * NS + s) * QKD + DNOPE;
      Kb[ob + 2 * p] = br;
      Kb[ob + 2 * p + 1] = bi;
    }
  }
}

// ---------------- flash attention: QBLK=128, 8 waves, async reg prefetch ----------------
__global__ __launch_bounds__(512) void k_attn(const bf16_t* __restrict__ Qb,
                                              const bf16_t* __restrict__ Kb,
                                              const bf16_t* __restrict__ Vtb,
                                              bf16_t* __restrict__ Ao) {
  __shared__ bf16x8 Ks[64 * 24];
  __shared__ bf16x8 Vs[128 * 8];
  __shared__ bf16x8 Ps[8 * 16 * 8];
  // XCD swizzle: 8 blocks of one (b,h) land on one XCD for K/V L2 reuse
  const int id = blockIdx.x;
  const int s_ = id >> 3;
  const int bh = (id & 7) + 8 * (s_ & 3);
  const int bx = s_ >> 2;  // 0..7 pair index
  const int b = bh >> 4, h = bh & 15;
  const int tid = threadIdx.x;
  const int lane = tid & 63, wave = tid >> 6;
  const int l15 = lane & 15, l4 = lane >> 4;
  const size_t bhNS = (size_t)bh * NS;
  const size_t bhDV = (size_t)bh * DVDIM;
  bf16_t* Pw = reinterpret_cast<bf16_t*>(&Ps[wave * 128]);
  const f32x4 Z4 = {0.f, 0.f, 0.f, 0.f};

  // staging decomposition (512 threads): K 1536 chunks x3, V 1024 chunks x2
  int krow[3], kkc[3], vrw[2], vkc[2];
#pragma unroll
  for (int i = 0; i < 3; ++i) {
    int c = tid + i * 512;
    krow[i] = c / 24;
    kkc[i] = c - krow[i] * 24;
  }
#pragma unroll
  for (int i = 0; i < 2; ++i) {
    int c = tid + i * 512;
    vrw[i] = c >> 3;
    vkc[i] = c & 7;
  }

#pragma unroll 1
  for (int phase = 0; phase < 2; ++phase) {
    const int qt = (phase == 0) ? (15 - bx) : bx;
    const int q0 = qt * 128;
    const int qrow = q0 + wave * 16;
    const int ntiles = 2 * qt + 2;

    bf16x8 qf[6];
    {
      const bf16_t* qrp = Qb + (bhNS + qrow + l15) * QKD;
#pragma unroll
      for (int kc = 0; kc < 6; ++kc)
        qf[kc] = reinterpret_cast<const bf16x8*>(qrp)[kc * 4 + l4];
    }

    f32x4 oacc[8];
#pragma unroll
    for (int i = 0; i < 8; ++i) oacc[i] = Z4;
    float mrun[4], lrun[4];
#pragma unroll
    for (int r = 0; r < 4; ++r) {
      mrun[r] = -3e38f;
      lrun[r] = 0.f;
    }

    // prefetch tile 0 into registers
    bf16x8 kpre[3], vpre[2];
#pragma unroll
    for (int i = 0; i < 3; ++i)
      kpre[i] = reinterpret_cast<const bf16x8*>(Kb + (bhNS + krow[i]) * QKD)[kkc[i]];
#pragma unroll
    for (int i = 0; i < 2; ++i)
      vpre[i] = reinterpret_cast<const bf16x8*>(Vtb + (bhDV + vrw[i]) * NS)[vkc[i]];

#pragma unroll 1
    for (int kt = 0; kt < ntiles; ++kt) {
      const int kv0 = kt * 64;
      __builtin_amdgcn_sched_barrier(0);
      __builtin_amdgcn_s_barrier();  // prev compute done reading LDS
      // commit prefetched tile to LDS (compiler inserts vmcnt waits)
#pragma unroll
      for (int i = 0; i < 3; ++i)
        Ks[krow[i] * 24 + ((kkc[i] & ~7) | ((kkc[i] ^ krow[i]) & 7))] = kpre[i];
#pragma unroll
      for (int i = 0; i < 2; ++i)
        Vs[vrw[i] * 8 + (vkc[i] ^ (vrw[i] & 7))] = vpre[i];
      // issue prefetch of next tile (overlaps with compute below)
      if (kt + 1 < ntiles) {
        const int nk = kv0 + 64;
#pragma unroll
        for (int i = 0; i < 3; ++i)
          kpre[i] = reinterpret_cast<const bf16x8*>(Kb + (bhNS + nk + krow[i]) * QKD)[kkc[i]];
#pragma unroll
        for (int i = 0; i < 2; ++i)
          vpre[i] = reinterpret_cast<const bf16x8*>(Vtb + (bhDV + vrw[i]) * NS + nk)[vkc[i]];
      }
      __builtin_amdgcn_sched_barrier(0);
      asm volatile("s_waitcnt lgkmcnt(0)" ::: "memory");
      __builtin_amdgcn_s_barrier();  // LDS ready
      __builtin_amdgcn_sched_barrier(0);

      if (qrow + 15 >= kv0) {  // wave has at least one unmasked row
        f32x4 sacc[4];
#pragma unroll
        for (int sub = 0; sub < 4; ++sub) {
          sacc[sub] = Z4;
#pragma unroll
          for (int ksc = 0; ksc < 6; ++ksc) {
            int row = sub * 16 + l15;
            int kc = ksc * 4 + l4;
            bf16x8 kf = Ks[row * 24 + ((kc & ~7) | ((kc ^ row) & 7))];
            sacc[sub] = __builtin_amdgcn_mfma_f32_16x16x32_bf16(qf[ksc], kf, sacc[sub], 0, 0, 0);
          }
        }

        float sbuf[4][4];
        float mloc[4] = {-3e38f, -3e38f, -3e38f, -3e38f};
        const bool msk = (kv0 >= q0);
#pragma unroll
        for (int sub = 0; sub < 4; ++sub) {
#pragma unroll
          for (int r = 0; r < 4; ++r) {
            float s = sacc[sub][r];
            if (msk) {
              int colg = kv0 + sub * 16 + l15;
              int rowg = qrow + l4 * 4 + r;
              if (colg > rowg) s = -3e38f;
            }
            sbuf[sub][r] = s;
            mloc[r] = fmaxf(mloc[r], s);
          }
        }
#pragma unroll
        for (int m = 1; m < 16; m <<= 1)
#pragma unroll
          for (int r = 0; r < 4; ++r) mloc[r] = fmaxf(mloc[r], __shfl_xor(mloc[r], m));

        float d0 = fmaxf(fmaxf(mloc[0] - mrun[0], mloc[1] - mrun[1]),
                         fmaxf(mloc[2] - mrun[2], mloc[3] - mrun[3]));
        if (!__all(d0 <= 0.f)) {
#pragma unroll
          for (int r = 0; r < 4; ++r) {
            float mn = fmaxf(mrun[r], mloc[r]);
            float fac = EXP2F(mrun[r] - mn);
            mrun[r] = mn;
            lrun[r] *= fac;
#pragma unroll
            for (int dc = 0; dc < 8; ++dc) oacc[dc][r] *= fac;
          }
        }

        float rsum[4] = {0.f, 0.f, 0.f, 0.f};
#pragma unroll
        for (int sub = 0; sub < 4; ++sub) {
#pragma unroll
          for (int r = 0; r < 4; ++r) {
            float p = EXP2F(sbuf[sub][r] - mrun[r]);
            rsum[r] += p;
            int prow = l4 * 4 + r;
            int pcol = sub * 16 + l15;
            Pw[prow * 64 + (((pcol >> 3) ^ (prow & 7)) << 3) + (pcol & 7)] = (bf16_t)p;
          }
        }
#pragma unroll
        for (int m = 1; m < 16; m <<= 1)
#pragma unroll
          for (int r = 0; r < 4; ++r) rsum[r] += __shfl_xor(rsum[r], m);
#pragma unroll
        for (int r = 0; r < 4; ++r) lrun[r] += rsum[r];

#pragma unroll
        for (int ks = 0; ks < 2; ++ks) {
          int kc = ks * 4 + l4;
          bf16x8 paf = reinterpret_cast<bf16x8*>(Pw)[l15 * 8 + (kc ^ (l15 & 7))];
#pragma unroll
          for (int dc = 0; dc < 8; ++dc) {
            int vrow = dc * 16 + l15;
            bf16x8 vf = Vs[vrow * 8 + (kc ^ (vrow & 7))];
            oacc[dc] = __builtin_amdgcn_mfma_f32_16x16x32_bf16(paf, vf, oacc[dc], 0, 0, 0);
          }
        }
      }
    }

#pragma unroll
    for (int r = 0; r < 4; ++r) lrun[r] = RCPF(lrun[r]);
#pragma unroll
    for (int dc = 0; dc < 8; ++dc) {
      int dv = dc * 16 + l15;
#pragma unroll
      for (int r = 0; r < 4; ++r) {
        int rowg = qrow + l4 * 4 + r;
        float v = oacc[dc][r] * lrun[r];
        Ao[((size_t)(b * NS + rowg)) * (NH * DVDIM) + h * DVDIM + dv] = (bf16_t)v;
      }
    }
  }
}

// ---------------- launch ----------------
extern "C" void kernel_launch(void* const* d_in, const int* in_sizes, int n_in,
                              void* d_out, int out_size, void* d_ws, size_t ws_size,
                              hipStream_t stream) {
  (void)in_sizes; (void)n_in; (void)out_size; (void)ws_size;
  const float* x = (const float*)d_in[0];
  const float* fcos = (const float*)d_in[1];
  const float* fsin = (const float*)d_in[2];
  const float* wq_a = (const float*)d_in[4];
  const float* q_norm_w = (const float*)d_in[5];
  const float* wq_b = (const float*)d_in[6];
  const float* wkv_a = (const float*)d_in[7];
  const float* kv_norm_w = (const float*)d_in[8];
  const float* wkv_b = (const float*)d_in[9];
  const float* wo = (const float*)d_in[10];
  float* out = (float*)d_out;

  // ws layout: wkva placed contiguously after wqa -> combined [2112,2048] weight
  char* p = (char*)d_ws;
  bf16_t* x_bf = (bf16_t*)(p);                 // 16,777,216
  bf16_t* wqa_bf = (bf16_t*)(p + 16777216);    //  6,291,456
  bf16_t* wkva_bf = (bf16_t*)(p + 23068672);   //  2,359,296 (contiguous with wqa)
  bf16_t* wqb_bf = (bf16_t*)(p + 25427968);    //  9,437,184
  bf16_t* wkvb_bf = (bf16_t*)(p + 34865152);   //  4,194,304
  bf16_t* wo_bf = (bf16_t*)(p + 39059456);     //  8,388,608
  float* qa_f32 = (float*)(p + 47448064);      // 25,165,824 (dead after rmsnorm)
  bf16_t* Kb = (bf16_t*)(p + 47448064);        // union with qa_f32
  bf16_t* qan_bf = (bf16_t*)(p + 72613888);    // 12,582,912
  bf16_t* Qb = (bf16_t*)(p + 85196800);        // 25,165,824
  char* r2 = p + 110362624;
  float* kvf_f32 = (float*)(r2);               //  9,437,184
  bf16_t* kvn_bf = (bf16_t*)(r2 + 9437184);    //  4,194,304
  bf16_t* Vtb = (bf16_t*)(r2 + 13631488);      // 16,777,216
  bf16_t* attn_bf = (bf16_t*)(r2 + 30408704);  // 16,777,216

  k_cvt_all<<<2048, 256, 0, stream>>>(x, wq_a, wq_b, wkv_a, wkv_b, wo, x_bf, wqa_bf,
                                      wqb_bf, wkva_bf, wkvb_bf, wo_bf);

  // merged: [q_a | kv_full] = x @ [wq_a; wkv_a]^T  [4096, 2112]
  k_gemm_bt<3><<<dim3(17, 32), 256, 0, stream>>>(x_bf, wqa_bf, qa_f32, kvf_f32,
                                                 nullptr, nullptr, nullptr, nullptr,
                                                 NB * NS, QLORA + KVLORA + DROPE, ND);
  k_rmsnorm<QLORA><<<NB * NS, 256, 0, stream>>>(qa_f32, q_norm_w, qan_bf);
  k_kv_post<<<NB * NS, 256, 0, stream>>>(kvf_f32, kv_norm_w, fcos, fsin, kvn_bf, Kb);
  // q = q_a_n @ wq_b^T [4096,3072] -> fused RoPE -> Qb [B*H,S,192]
  k_gemm_bt<2><<<dim3(24, 32), 256, 0, stream>>>(qan_bf, wqb_bf, nullptr, nullptr, Qb,
                                                 nullptr, fcos, fsin, NB * NS, NH * QKD,
                                                 QLORA);
  // kv_b = kv_n @ wkv_b^T [4096,4096] -> scatter K (nope) + V^T
  k_gemm_bt<1><<<dim3(32, 32), 256, 0, stream>>>(kvn_bf, wkvb_bf, nullptr, nullptr, Kb,
                                                 Vtb, nullptr, nullptr, NB * NS,
                                                 NH * (DNOPE + DVDIM), KVLORA);
  // attention: QBLK=128, supertile pairs, grid 256 x 512 threads
  k_attn<<<dim3(256), 512, 0, stream>>>(Qb, Kb, Vtb, attn_bf);
  // out = attn @ wo^T  [4096,2048] f32
  k_gemm_bt<0><<<dim3(16, 32), 256, 0, stream>>>(attn_bf, wo_bf, out, nullptr, nullptr,
                                                 nullptr, nullptr, nullptr, NB * NS, ND,
                                                 NH * DVDIM);
}